// Round 2
// baseline (1108.878 us; speedup 1.0000x reference)
//
#include <hip/hip_runtime.h>
#include <math.h>

typedef unsigned short ushort_t;
typedef __attribute__((ext_vector_type(8))) short bf16x8_t;   // 8 bf16 in 4 VGPRs
typedef __attribute__((ext_vector_type(4))) float floatx4;

typedef __attribute__((address_space(3))) unsigned int lds_uint;
typedef const __attribute__((address_space(1))) unsigned int glob_uint;

__device__ inline void gl_lds16(const ushort_t* g, ushort_t* l) {
    // async global->LDS, 16B/lane; LDS dest = wave-uniform base + lane*16
    __builtin_amdgcn_global_load_lds((glob_uint*)g, (lds_uint*)l, 16, 0, 0);
}

__device__ inline float bf2f(ushort_t u) {
    return __uint_as_float(((unsigned int)u) << 16);
}
__device__ inline ushort_t f2bf(float f) {
    unsigned int u = __float_as_uint(f);
    unsigned int r = (u + 0x7fffu + ((u >> 16) & 1u)) >> 16;   // RNE
    return (ushort_t)r;
}
__device__ inline float wave_sum(float v) {
    #pragma unroll
    for (int m = 1; m < 64; m <<= 1) v += __shfl_xor(v, m, 64);
    return v;
}

// ---------------- transpose W[K][N] -> WT_h/WT_l[N][K] (fp32 -> split bf16) ----------------
__global__ __launch_bounds__(256) void transpose_split(const float* __restrict__ W,
                                                       ushort_t* __restrict__ WTh,
                                                       ushort_t* __restrict__ WTl,
                                                       int K, int N) {
    __shared__ float t[32][33];
    int n0 = blockIdx.x * 32, k0 = blockIdx.y * 32;
    int tx = threadIdx.x, ty = threadIdx.y;
    for (int i = ty; i < 32; i += 8)
        t[i][tx] = W[(size_t)(k0 + i) * N + n0 + tx];
    __syncthreads();
    for (int i = ty; i < 32; i += 8) {
        float v = t[tx][i];
        ushort_t hv = f2bf(v);
        size_t o = (size_t)(n0 + i) * K + k0 + tx;
        WTh[o] = hv;
        WTl[o] = f2bf(v - bf2f(hv));
    }
}

// ---------------- LayerNorm + split both xn and raw x into hi/lo bf16 ----------------
__global__ __launch_bounds__(256) void ln_split(const float* __restrict__ x,
                                                const float* __restrict__ gamma,
                                                ushort_t* __restrict__ xnh,
                                                ushort_t* __restrict__ xnl,
                                                ushort_t* __restrict__ xh,
                                                ushort_t* __restrict__ xl) {
    int row = blockIdx.x, tid = threadIdx.x;
    int wid = tid >> 6, lane = tid & 63;
    float v[4];
    float s1 = 0.f, s2 = 0.f;
    #pragma unroll
    for (int i = 0; i < 4; ++i) {
        v[i] = x[(size_t)row * 1024 + tid + 256 * i];
        s1 += v[i];
        s2 += v[i] * v[i];
    }
    s1 = wave_sum(s1);
    s2 = wave_sum(s2);
    __shared__ float red[8];
    if (lane == 0) { red[wid] = s1; red[4 + wid] = s2; }
    __syncthreads();
    float S1 = red[0] + red[1] + red[2] + red[3];
    float S2 = red[4] + red[5] + red[6] + red[7];
    float mu = S1 * (1.0f / 1024.0f);
    float var = S2 * (1.0f / 1024.0f) - mu * mu;
    float rs = 1.0f / sqrtf(var + 1e-5f);
    #pragma unroll
    for (int i = 0; i < 4; ++i) {
        int c = tid + 256 * i;
        size_t o = (size_t)row * 1024 + c;
        ushort_t hx = f2bf(v[i]);
        xh[o] = hx;
        xl[o] = f2bf(v[i] - bf2f(hx));
        float xnv = (v[i] - mu) * rs * gamma[c];
        ushort_t hn = f2bf(xnv);
        xnh[o] = hn;
        xnl[o] = f2bf(xnv - bf2f(hn));
    }
}

// ---------------- GEMM: C[M][N] = (Ah+Al)[M][K] * (Bh+Bl)[N][K]^T, 3-term split ----------------
// LDS rows interleave [hi 32 | lo 32] u16 chunks, XOR-swizzled (cc^(r&7)) so frag
// ds_read_b128 are conflict-free; staged via global_load_lds width=16.
// Double-buffered: stage(kt+1) issued at top of iter kt so the vmcnt(0) drain at
// the single end-of-iter barrier is covered by that iteration's MFMA work.
__global__ __launch_bounds__(256) void gemm_bf3(const ushort_t* __restrict__ Ah,
                                                const ushort_t* __restrict__ Al,
                                                const ushort_t* __restrict__ Bh,
                                                const ushort_t* __restrict__ Bl,
                                                float* __restrict__ C,
                                                int M, int N, int K) {
    __shared__ ushort_t As[2][128 * 64];
    __shared__ ushort_t Bs[2][128 * 64];
    int tid = threadIdx.x;
    int w = tid >> 6, lane = tid & 63;
    int wm = w >> 1, wn = w & 1;
    int row0 = blockIdx.y * 128, col0 = blockIdx.x * 128;
    int l15 = lane & 15, l4 = lane >> 4;
    int rx = l15 & 7;
    floatx4 acc[4][4];
    #pragma unroll
    for (int i = 0; i < 4; ++i)
        #pragma unroll
        for (int j = 0; j < 4; ++j)
            #pragma unroll
            for (int v = 0; v < 4; ++v) acc[i][j][v] = 0.f;

    auto stage = [&](int kt, int bufi) {
        #pragma unroll
        for (int c = 0; c < 4; ++c) {
            int idx = c * 256 + tid;
            int r = idx >> 3, cl = idx & 7;
            int cg = cl ^ (r & 7);                         // content chunk
            const ushort_t* ga = (cg < 4 ? Ah : Al)
                + (size_t)(row0 + r) * K + kt * 32 + (cg & 3) * 8;
            gl_lds16(ga, &As[bufi][(c * 256 + w * 64) * 8]);
            const ushort_t* gb = (cg < 4 ? Bh : Bl)
                + (size_t)(col0 + r) * K + kt * 32 + (cg & 3) * 8;
            gl_lds16(gb, &Bs[bufi][(c * 256 + w * 64) * 8]);
        }
    };

    int nk = K >> 5;
    stage(0, 0);
    __syncthreads();                       // drains tile-0 staging
    for (int kt = 0; kt < nk; ++kt) {
        int cur = kt & 1;
        if (kt + 1 < nk) stage(kt + 1, cur ^ 1);   // latency hidden under this iter
        bf16x8_t af_h[4], af_l[4], bf_h[4], bf_l[4];
        #pragma unroll
        for (int mi = 0; mi < 4; ++mi) {
            int r = wm * 64 + mi * 16 + l15;
            af_h[mi] = *(const bf16x8_t*)&As[cur][(r * 8 + (l4 ^ rx)) * 8];
            af_l[mi] = *(const bf16x8_t*)&As[cur][(r * 8 + ((4 + l4) ^ rx)) * 8];
        }
        #pragma unroll
        for (int ni = 0; ni < 4; ++ni) {
            int r = wn * 64 + ni * 16 + l15;
            bf_h[ni] = *(const bf16x8_t*)&Bs[cur][(r * 8 + (l4 ^ rx)) * 8];
            bf_l[ni] = *(const bf16x8_t*)&Bs[cur][(r * 8 + ((4 + l4) ^ rx)) * 8];
        }
        #pragma unroll
        for (int mi = 0; mi < 4; ++mi)
            #pragma unroll
            for (int ni = 0; ni < 4; ++ni) {
                acc[mi][ni] = __builtin_amdgcn_mfma_f32_16x16x32_bf16(
                    af_h[mi], bf_h[ni], acc[mi][ni], 0, 0, 0);
                acc[mi][ni] = __builtin_amdgcn_mfma_f32_16x16x32_bf16(
                    af_h[mi], bf_l[ni], acc[mi][ni], 0, 0, 0);
                acc[mi][ni] = __builtin_amdgcn_mfma_f32_16x16x32_bf16(
                    af_l[mi], bf_h[ni], acc[mi][ni], 0, 0, 0);
            }
        __syncthreads();       // next buf staged AND protects cur for overwrite
    }
    #pragma unroll
    for (int mi = 0; mi < 4; ++mi)
        #pragma unroll
        for (int ni = 0; ni < 4; ++ni)
            #pragma unroll
            for (int v = 0; v < 4; ++v) {
                int rr = row0 + wm * 64 + mi * 16 + l4 * 4 + v;
                int cc = col0 + wn * 64 + ni * 16 + l15;
                C[(size_t)rr * N + cc] = acc[mi][ni][v];
            }
}

// ---------------- q: l2norm * q_scale * 8 -> split bf16 [bh][2048][64] ----------------
__global__ __launch_bounds__(256) void l2scale_q(const float* __restrict__ q,
                                                 const float* __restrict__ qs,
                                                 ushort_t* __restrict__ Qh,
                                                 ushort_t* __restrict__ Ql) {
    int rid = blockIdx.x * 4 + (threadIdx.x >> 6);
    int lane = threadIdx.x & 63;
    int h = rid & 15, n = (rid >> 4) & 2047, b = rid >> 15;
    float v = q[(size_t)rid * 64 + lane];
    float nrm = sqrtf(wave_sum(v * v));
    float qn = v / fmaxf(nrm, 1e-12f) * qs[lane] * 8.0f;
    size_t o = (((size_t)(b * 16 + h)) * 2048 + n) * 64 + lane;
    ushort_t hv = f2bf(qn);
    Qh[o] = hv;
    Ql[o] = f2bf(qn - bf2f(hv));
}

// ---------------- build K split [bh][2112][64], V^T hi [bh][64][2112] (coalesced) ----------------
__global__ __launch_bounds__(256) void build_kv(const float* __restrict__ kv,
                                                const float* __restrict__ nullkv,
                                                const float* __restrict__ ks,
                                                ushort_t* __restrict__ Kh,
                                                ushort_t* __restrict__ Kl,
                                                ushort_t* __restrict__ VTh) {
    __shared__ ushort_t Vt[64][72];     // [j][d]
    int tid = threadIdx.x;
    int w = tid >> 6, lane = tid & 63;
    int bh = blockIdx.y, b = bh >> 4, h = bh & 15;
    int j0 = blockIdx.x * 64;
    for (int jj = 0; jj < 16; ++jj) {
        int jl = w * 16 + jj;
        int j = j0 + jl;
        float kf = 0.f, vf = 0.f;
        if (j < 2) {
            kf = nullkv[(h * 4 + 2 * j) * 64 + lane];
            vf = nullkv[(h * 4 + 2 * j + 1) * 64 + lane];
        } else if (j < 2050) {
            int n = j - 2;
            size_t base = ((size_t)b * 2048 + n) * 2048;
            kf = kv[base + h * 64 + lane];
            vf = kv[base + 1024 + h * 64 + lane];
        }
        float nrm = sqrtf(wave_sum(kf * kf));
        float kn = (j < 2050) ? kf / fmaxf(nrm, 1e-12f) * ks[lane] : 0.f;
        size_t o = ((size_t)bh * 2112 + j) * 64 + lane;
        ushort_t khv = f2bf(kn);
        Kh[o] = khv;
        Kl[o] = f2bf(kn - bf2f(khv));
        Vt[jl][lane] = f2bf(vf);
    }
    __syncthreads();
    int d = tid >> 2, seg = tid & 3;    // thread writes VT[d][j0+seg*16 .. +15]
    ushort_t buf[16];
    #pragma unroll
    for (int e = 0; e < 16; ++e) buf[e] = Vt[seg * 16 + e][d];
    size_t o = ((size_t)bh * 64 + d) * 2112 + j0 + seg * 16;
    *(bf16x8_t*)&VTh[o]     = *(const bf16x8_t*)&buf[0];
    *(bf16x8_t*)&VTh[o + 8] = *(const bf16x8_t*)&buf[8];
}

// ---------------- MFMA flash attention, static-max softmax, software-pipelined ----------------
// p = exp(s + bias - 16): |s|<=8, bias tail < 6 -> arg < 0 always; softmax is
// scale-invariant so no running max / rescale is needed. QK = (qh+ql)*kh + qh*kl.
// PV = ph*vh. K double-buffered in LDS (staged one iter ahead); V B-frags read
// DIRECTLY from global VTh (L2-resident: 270 KB/bh, shared by 32 qt-blocks) at
// the top of each iter so L2 latency hides under QK+exp. Bias prefetched one
// iter ahead with mask+causal+(-16)+log2e pre-folded: p = exp2(fma(s,log2e,bv)).
// LDS 41 KB -> 3 blocks/CU (was 57 KB / 2 with V staged).
__global__ __launch_bounds__(256, 3) void attn_mfma(const ushort_t* __restrict__ Qh,
                                                    const ushort_t* __restrict__ Ql,
                                                    const ushort_t* __restrict__ Kh,
                                                    const ushort_t* __restrict__ Kl,
                                                    const ushort_t* __restrict__ VTh,
                                                    const float* __restrict__ bias,
                                                    const int* __restrict__ mask,
                                                    ushort_t* __restrict__ aoh,
                                                    ushort_t* __restrict__ aol) {
    __shared__ ushort_t Ks[2][64 * 128];   // row j: [kh 64 | kl 64], 16 chunks swizzled
    __shared__ ushort_t Ps[4][16 * 72];

    int tid = threadIdx.x;
    int w = tid >> 6, lane = tid & 63;
    int quad = lane >> 4, l15 = lane & 15;
    int rx = l15 & 7;
    int qt = 31 - blockIdx.x;           // longest blocks first (causal imbalance)
    int bh = blockIdx.y;
    int b = bh >> 4, h = bh & 15;
    int i0 = qt * 64, r0 = i0 + w * 16;
    const int nIter = qt + 2;           // j-tiles: j0 = 0,64,...,(qt+1)*64

    // --- staging: K (4 chunks) for one j-tile into given buffer ---
    auto stageK = [&](int j0, ushort_t* kd) {
        #pragma unroll
        for (int c = 0; c < 4; ++c) {        // K: 1024 chunks
            int idx = c * 256 + tid;
            int r = idx >> 4, cl = idx & 15;
            int cg = (cl & 8) | ((cl ^ (r & 7)) & 7);
            const ushort_t* g = ((cg & 8) ? Kl : Kh)
                + ((size_t)bh * 2112 + j0 + r) * 64 + (cg & 7) * 8;
            gl_lds16(g, &kd[(c * 256 + w * 64) * 8]);
        }
    };

    // --- register prefetch of bias for one j-tile; mask/causal/-16/log2e folded ---
    float bv_n[4][4];
    auto prefetchB = [&](int j0n) {
        #pragma unroll
        for (int jt = 0; jt < 4; ++jt) {
            int jg = j0n + jt * 16 + l15;
            int km = (jg < 2) ? 1 : (jg < 2050 ? mask[b * 2048 + jg - 2] : 0);
            #pragma unroll
            for (int reg = 0; reg < 4; ++reg) {
                int ig = r0 + quad * 4 + reg;
                float bvv = (jg >= 2 && jg < 2050)
                    ? bias[((size_t)h * 2048 + ig) * 2048 + (jg - 2)] : 0.f;
                bool ok = (km != 0) && (jg <= ig + 2);
                bv_n[jt][reg] = ok ? (bvv - 16.0f) * 1.442695041f : -1e30f;
            }
        }
    };

    // issue tile-0 staging + prefetch first, then overlap Q-frag loads with it
    stageK(0, Ks[0]);
    prefetchB(0);

    bf16x8_t aqh[2], aql[2];
    {
        size_t qbase = ((size_t)bh * 2048 + r0 + l15) * 64 + quad * 8;
        aqh[0] = *(const bf16x8_t*)&Qh[qbase];
        aqh[1] = *(const bf16x8_t*)&Qh[qbase + 32];
        aql[0] = *(const bf16x8_t*)&Ql[qbase];
        aql[1] = *(const bf16x8_t*)&Ql[qbase + 32];
    }

    floatx4 o_acc[4];
    float l_acc[4];
    #pragma unroll
    for (int dt = 0; dt < 4; ++dt)
        #pragma unroll
        for (int v = 0; v < 4; ++v) o_acc[dt][v] = 0.f;
    #pragma unroll
    for (int r = 0; r < 4; ++r) l_acc[r] = 0.f;

    const ushort_t* vb = VTh + (size_t)bh * 64 * 2112;

    __syncthreads();                      // drains tile-0 staging (vmcnt 0)

    for (int it = 0; it < nIter; ++it) {
        int cur = it & 1;
        int j0 = it * 64;

        // V B-frags for CURRENT tile, direct from global (L2); latency hides
        // under the QK + exp phases below.
        bf16x8_t vfr[2][4];
        #pragma unroll
        for (int ks2 = 0; ks2 < 2; ++ks2)
            #pragma unroll
            for (int dt = 0; dt < 4; ++dt)
                vfr[ks2][dt] = *(const bf16x8_t*)
                    &vb[(size_t)(dt * 16 + l15) * 2112 + j0 + ks2 * 32 + quad * 8];

        // rotate prefetched bias into current regs, then issue next prefetch/stage
        float bv[4][4];
        #pragma unroll
        for (int jt = 0; jt < 4; ++jt)
            #pragma unroll
            for (int reg = 0; reg < 4; ++reg) bv[jt][reg] = bv_n[jt][reg];
        if (it + 1 < nIter) {
            stageK(j0 + 64, Ks[cur ^ 1]);   // latency hidden under this iter
            prefetchB(j0 + 64);
        }
        const ushort_t* ks = Ks[cur];

        // S = Q K^T  (C-layout: row i = quad*4+reg, col j = jt*16+l15)
        floatx4 s_acc[4];
        #pragma unroll
        for (int jt = 0; jt < 4; ++jt) {
            floatx4 acc;
            #pragma unroll
            for (int v = 0; v < 4; ++v) acc[v] = 0.f;
            int r = jt * 16 + l15;
            #pragma unroll
            for (int ks2 = 0; ks2 < 2; ++ks2) {
                int cc = ks2 * 4 + quad;
                bf16x8_t kbh = *(const bf16x8_t*)&ks[(r * 16 + (cc ^ rx)) * 8];
                bf16x8_t kbl = *(const bf16x8_t*)&ks[(r * 16 + 8 + (cc ^ rx)) * 8];
                acc = __builtin_amdgcn_mfma_f32_16x16x32_bf16(aqh[ks2], kbh, acc, 0, 0, 0);
                acc = __builtin_amdgcn_mfma_f32_16x16x32_bf16(aql[ks2], kbh, acc, 0, 0, 0);
                acc = __builtin_amdgcn_mfma_f32_16x16x32_bf16(aqh[ks2], kbl, acc, 0, 0, 0);
            }
            s_acc[jt] = acc;
        }

        // p = exp2(fma(s, log2e, bv)); bv already has mask/causal/-16 folded
        #pragma unroll
        for (int jt = 0; jt < 4; ++jt) {
            #pragma unroll
            for (int reg = 0; reg < 4; ++reg) {
                float pv = exp2f(fmaf(s_acc[jt][reg], 1.442695041f, bv[jt][reg]));
                l_acc[reg] += pv;
                Ps[w][(quad * 4 + reg) * 72 + jt * 16 + l15] = f2bf(pv);
            }
        }

        // PV: P A-frags (same-wave LDS round-trip, no barrier needed), V from regs
        #pragma unroll
        for (int ks2 = 0; ks2 < 2; ++ks2) {
            bf16x8_t pf = *(const bf16x8_t*)&Ps[w][l15 * 72 + ks2 * 32 + quad * 8];
            #pragma unroll
            for (int dt = 0; dt < 4; ++dt)
                o_acc[dt] = __builtin_amdgcn_mfma_f32_16x16x32_bf16(
                    pf, vfr[ks2][dt], o_acc[dt], 0, 0, 0);
        }

        // single barrier: drains next-tile K staging AND protects buffer reuse
        __syncthreads();
    }

    // reduce l over the 16 l15 lanes (lane bits 0..3), rows = quad*4+reg
    #pragma unroll
    for (int reg = 0; reg < 4; ++reg) {
        #pragma unroll
        for (int m2 = 1; m2 < 16; m2 <<= 1)
            l_acc[reg] += __shfl_xor(l_acc[reg], m2, 64);
    }
    #pragma unroll
    for (int dt = 0; dt < 4; ++dt)
        #pragma unroll
        for (int reg = 0; reg < 4; ++reg) {
            int ig = r0 + quad * 4 + reg;
            float ov = o_acc[dt][reg] / l_acc[reg];
            size_t o = ((size_t)b * 2048 + ig) * 1024 + h * 64 + dt * 16 + l15;
            ushort_t hv = f2bf(ov);
            aoh[o] = hv;
            aol[o] = f2bf(ov - bf2f(hv));
        }
}

extern "C" void kernel_launch(void* const* d_in, const int* in_sizes, int n_in,
                              void* d_out, int out_size, void* d_ws, size_t ws_size,
                              hipStream_t stream) {
    const float* x         = (const float*)d_in[0];
    const int*   mask      = (const int*)d_in[1];
    const float* attn_bias = (const float*)d_in[2];
    const float* gamma     = (const float*)d_in[3];
    const float* null_kv   = (const float*)d_in[4];
    const float* Wq        = (const float*)d_in[5];
    const float* Wkv       = (const float*)d_in[6];
    const float* q_scale   = (const float*)d_in[7];
    const float* k_scale   = (const float*)d_in[8];
    const float* Wo        = (const float*)d_in[9];

    char* ws = (char*)d_ws;
    ushort_t* xnh   = (ushort_t*)ws; ws += (size_t)4096 * 1024 * 2;
    ushort_t* xnl   = (ushort_t*)ws; ws += (size_t)4096 * 1024 * 2;
    ushort_t* xh    = (ushort_t*)ws; ws += (size_t)4096 * 1024 * 2;
    ushort_t* xl    = (ushort_t*)ws; ws += (size_t)4096 * 1024 * 2;
    ushort_t* WqTh  = (ushort_t*)ws; ws += (size_t)1024 * 1024 * 2;
    ushort_t* WqTl  = (ushort_t*)ws; ws += (size_t)1024 * 1024 * 2;
    ushort_t* WkvTh = (ushort_t*)ws; ws += (size_t)2048 * 1024 * 2;
    ushort_t* WkvTl = (ushort_t*)ws; ws += (size_t)2048 * 1024 * 2;
    ushort_t* WoTh  = (ushort_t*)ws; ws += (size_t)1024 * 1024 * 2;
    ushort_t* WoTl  = (ushort_t*)ws; ws += (size_t)1024 * 1024 * 2;
    float*    q_ws  = (float*)ws;    ws += (size_t)4096 * 1024 * 4;
    float*    kvws  = (float*)ws;    ws += (size_t)4096 * 2048 * 4;
    ushort_t* Qh    = (ushort_t*)ws; ws += (size_t)32 * 2048 * 64 * 2;
    ushort_t* Ql    = (ushort_t*)ws; ws += (size_t)32 * 2048 * 64 * 2;
    ushort_t* Kh    = (ushort_t*)ws; ws += (size_t)32 * 2112 * 64 * 2;
    ushort_t* Kl    = (ushort_t*)ws; ws += (size_t)32 * 2112 * 64 * 2;
    ushort_t* VTh   = (ushort_t*)ws; ws += (size_t)32 * 2112 * 64 * 2;
    ushort_t* aoh   = (ushort_t*)ws; ws += (size_t)4096 * 1024 * 2;
    ushort_t* aol   = (ushort_t*)ws; ws += (size_t)4096 * 1024 * 2;

    transpose_split<<<dim3(32, 32), dim3(32, 8), 0, stream>>>(Wq, WqTh, WqTl, 1024, 1024);
    transpose_split<<<dim3(64, 32), dim3(32, 8), 0, stream>>>(Wkv, WkvTh, WkvTl, 1024, 2048);
    transpose_split<<<dim3(32, 32), dim3(32, 8), 0, stream>>>(Wo, WoTh, WoTl, 1024, 1024);
    ln_split<<<4096, 256, 0, stream>>>(x, gamma, xnh, xnl, xh, xl);
    gemm_bf3<<<dim3(8, 32), 256, 0, stream>>>(xnh, xnl, WqTh, WqTl, q_ws, 4096, 1024, 1024);
    gemm_bf3<<<dim3(16, 32), 256, 0, stream>>>(xh, xl, WkvTh, WkvTl, kvws, 4096, 2048, 1024);
    l2scale_q<<<16384, 256, 0, stream>>>(q_ws, q_scale, Qh, Ql);
    build_kv<<<dim3(33, 32), 256, 0, stream>>>(kvws, null_kv, k_scale, Kh, Kl, VTh);
    attn_mfma<<<dim3(32, 32), 256, 0, stream>>>(Qh, Ql, Kh, Kl, VTh, attn_bias, mask, aoh, aol);
    gemm_bf3<<<dim3(8, 32), 256, 0, stream>>>(aoh, aol, WoTh, WoTl, (float*)d_out, 4096, 1024, 1024);
}

// Round 3
// 900.056 us; speedup vs baseline: 1.2320x; 1.2320x over previous
//
#include <hip/hip_runtime.h>
#include <math.h>

typedef unsigned short ushort_t;
typedef __attribute__((ext_vector_type(8))) short bf16x8_t;   // 8 bf16 in 4 VGPRs
typedef __attribute__((ext_vector_type(4))) float floatx4;

typedef __attribute__((address_space(3))) unsigned int lds_uint;
typedef const __attribute__((address_space(1))) unsigned int glob_uint;

__device__ inline void gl_lds16(const ushort_t* g, ushort_t* l) {
    // async global->LDS, 16B/lane; LDS dest = wave-uniform base + lane*16
    __builtin_amdgcn_global_load_lds((glob_uint*)g, (lds_uint*)l, 16, 0, 0);
}

__device__ inline float bf2f(ushort_t u) {
    return __uint_as_float(((unsigned int)u) << 16);
}
__device__ inline ushort_t f2bf(float f) {
    unsigned int u = __float_as_uint(f);
    unsigned int r = (u + 0x7fffu + ((u >> 16) & 1u)) >> 16;   // RNE
    return (ushort_t)r;
}
__device__ inline float wave_sum(float v) {
    #pragma unroll
    for (int m = 1; m < 64; m <<= 1) v += __shfl_xor(v, m, 64);
    return v;
}

// ---------------- transpose W[K][N] -> WT_h/WT_l[N][K] (fp32 -> split bf16) ----------------
__global__ __launch_bounds__(256) void transpose_split(const float* __restrict__ W,
                                                       ushort_t* __restrict__ WTh,
                                                       ushort_t* __restrict__ WTl,
                                                       int K, int N) {
    __shared__ float t[32][33];
    int n0 = blockIdx.x * 32, k0 = blockIdx.y * 32;
    int tx = threadIdx.x, ty = threadIdx.y;
    for (int i = ty; i < 32; i += 8)
        t[i][tx] = W[(size_t)(k0 + i) * N + n0 + tx];
    __syncthreads();
    for (int i = ty; i < 32; i += 8) {
        float v = t[tx][i];
        ushort_t hv = f2bf(v);
        size_t o = (size_t)(n0 + i) * K + k0 + tx;
        WTh[o] = hv;
        WTl[o] = f2bf(v - bf2f(hv));
    }
}

// ---------------- LayerNorm + split both xn and raw x into hi/lo bf16 ----------------
__global__ __launch_bounds__(256) void ln_split(const float* __restrict__ x,
                                                const float* __restrict__ gamma,
                                                ushort_t* __restrict__ xnh,
                                                ushort_t* __restrict__ xnl,
                                                ushort_t* __restrict__ xh,
                                                ushort_t* __restrict__ xl) {
    int row = blockIdx.x, tid = threadIdx.x;
    int wid = tid >> 6, lane = tid & 63;
    float v[4];
    float s1 = 0.f, s2 = 0.f;
    #pragma unroll
    for (int i = 0; i < 4; ++i) {
        v[i] = x[(size_t)row * 1024 + tid + 256 * i];
        s1 += v[i];
        s2 += v[i] * v[i];
    }
    s1 = wave_sum(s1);
    s2 = wave_sum(s2);
    __shared__ float red[8];
    if (lane == 0) { red[wid] = s1; red[4 + wid] = s2; }
    __syncthreads();
    float S1 = red[0] + red[1] + red[2] + red[3];
    float S2 = red[4] + red[5] + red[6] + red[7];
    float mu = S1 * (1.0f / 1024.0f);
    float var = S2 * (1.0f / 1024.0f) - mu * mu;
    float rs = 1.0f / sqrtf(var + 1e-5f);
    #pragma unroll
    for (int i = 0; i < 4; ++i) {
        int c = tid + 256 * i;
        size_t o = (size_t)row * 1024 + c;
        ushort_t hx = f2bf(v[i]);
        xh[o] = hx;
        xl[o] = f2bf(v[i] - bf2f(hx));
        float xnv = (v[i] - mu) * rs * gamma[c];
        ushort_t hn = f2bf(xnv);
        xnh[o] = hn;
        xnl[o] = f2bf(xnv - bf2f(hn));
    }
}

// ---------------- GEMM: C[M][N] = (Ah+Al)[M][K] * (Bh+Bl)[N][K]^T, 3-term split ----------------
// LDS rows interleave [hi 32 | lo 32] u16 chunks, XOR-swizzled (cc^(r&7)) so frag
// ds_read_b128 are conflict-free; staged via global_load_lds width=16.
// Double-buffered: stage(kt+1) issued at top of iter kt so the vmcnt(0) drain at
// the single end-of-iter barrier is covered by that iteration's MFMA work.
__global__ __launch_bounds__(256) void gemm_bf3(const ushort_t* __restrict__ Ah,
                                                const ushort_t* __restrict__ Al,
                                                const ushort_t* __restrict__ Bh,
                                                const ushort_t* __restrict__ Bl,
                                                float* __restrict__ C,
                                                int M, int N, int K) {
    __shared__ ushort_t As[2][128 * 64];
    __shared__ ushort_t Bs[2][128 * 64];
    int tid = threadIdx.x;
    int w = tid >> 6, lane = tid & 63;
    int wm = w >> 1, wn = w & 1;
    int row0 = blockIdx.y * 128, col0 = blockIdx.x * 128;
    int l15 = lane & 15, l4 = lane >> 4;
    int rx = l15 & 7;
    floatx4 acc[4][4];
    #pragma unroll
    for (int i = 0; i < 4; ++i)
        #pragma unroll
        for (int j = 0; j < 4; ++j)
            #pragma unroll
            for (int v = 0; v < 4; ++v) acc[i][j][v] = 0.f;

    auto stage = [&](int kt, int bufi) {
        #pragma unroll
        for (int c = 0; c < 4; ++c) {
            int idx = c * 256 + tid;
            int r = idx >> 3, cl = idx & 7;
            int cg = cl ^ (r & 7);                         // content chunk
            const ushort_t* ga = (cg < 4 ? Ah : Al)
                + (size_t)(row0 + r) * K + kt * 32 + (cg & 3) * 8;
            gl_lds16(ga, &As[bufi][(c * 256 + w * 64) * 8]);
            const ushort_t* gb = (cg < 4 ? Bh : Bl)
                + (size_t)(col0 + r) * K + kt * 32 + (cg & 3) * 8;
            gl_lds16(gb, &Bs[bufi][(c * 256 + w * 64) * 8]);
        }
    };

    int nk = K >> 5;
    stage(0, 0);
    __syncthreads();                       // drains tile-0 staging
    for (int kt = 0; kt < nk; ++kt) {
        int cur = kt & 1;
        if (kt + 1 < nk) stage(kt + 1, cur ^ 1);   // latency hidden under this iter
        bf16x8_t af_h[4], af_l[4], bf_h[4], bf_l[4];
        #pragma unroll
        for (int mi = 0; mi < 4; ++mi) {
            int r = wm * 64 + mi * 16 + l15;
            af_h[mi] = *(const bf16x8_t*)&As[cur][(r * 8 + (l4 ^ rx)) * 8];
            af_l[mi] = *(const bf16x8_t*)&As[cur][(r * 8 + ((4 + l4) ^ rx)) * 8];
        }
        #pragma unroll
        for (int ni = 0; ni < 4; ++ni) {
            int r = wn * 64 + ni * 16 + l15;
            bf_h[ni] = *(const bf16x8_t*)&Bs[cur][(r * 8 + (l4 ^ rx)) * 8];
            bf_l[ni] = *(const bf16x8_t*)&Bs[cur][(r * 8 + ((4 + l4) ^ rx)) * 8];
        }
        #pragma unroll
        for (int mi = 0; mi < 4; ++mi)
            #pragma unroll
            for (int ni = 0; ni < 4; ++ni) {
                acc[mi][ni] = __builtin_amdgcn_mfma_f32_16x16x32_bf16(
                    af_h[mi], bf_h[ni], acc[mi][ni], 0, 0, 0);
                acc[mi][ni] = __builtin_amdgcn_mfma_f32_16x16x32_bf16(
                    af_h[mi], bf_l[ni], acc[mi][ni], 0, 0, 0);
                acc[mi][ni] = __builtin_amdgcn_mfma_f32_16x16x32_bf16(
                    af_l[mi], bf_h[ni], acc[mi][ni], 0, 0, 0);
            }
        __syncthreads();       // next buf staged AND protects cur for overwrite
    }
    #pragma unroll
    for (int mi = 0; mi < 4; ++mi)
        #pragma unroll
        for (int ni = 0; ni < 4; ++ni)
            #pragma unroll
            for (int v = 0; v < 4; ++v) {
                int rr = row0 + wm * 64 + mi * 16 + l4 * 4 + v;
                int cc = col0 + wn * 64 + ni * 16 + l15;
                C[(size_t)rr * N + cc] = acc[mi][ni][v];
            }
}

// ---------------- q: l2norm * q_scale * 8 -> split bf16 [bh][2048][64] ----------------
__global__ __launch_bounds__(256) void l2scale_q(const float* __restrict__ q,
                                                 const float* __restrict__ qs,
                                                 ushort_t* __restrict__ Qh,
                                                 ushort_t* __restrict__ Ql) {
    int rid = blockIdx.x * 4 + (threadIdx.x >> 6);
    int lane = threadIdx.x & 63;
    int h = rid & 15, n = (rid >> 4) & 2047, b = rid >> 15;
    float v = q[(size_t)rid * 64 + lane];
    float nrm = sqrtf(wave_sum(v * v));
    float qn = v / fmaxf(nrm, 1e-12f) * qs[lane] * 8.0f;
    size_t o = (((size_t)(b * 16 + h)) * 2048 + n) * 64 + lane;
    ushort_t hv = f2bf(qn);
    Qh[o] = hv;
    Ql[o] = f2bf(qn - bf2f(hv));
}

// ---------------- build K split [bh][2112][64], V^T hi [bh][64][2112] (coalesced) ----------------
__global__ __launch_bounds__(256) void build_kv(const float* __restrict__ kv,
                                                const float* __restrict__ nullkv,
                                                const float* __restrict__ ks,
                                                ushort_t* __restrict__ Kh,
                                                ushort_t* __restrict__ Kl,
                                                ushort_t* __restrict__ VTh) {
    __shared__ ushort_t Vt[64][72];     // [j][d]
    int tid = threadIdx.x;
    int w = tid >> 6, lane = tid & 63;
    int bh = blockIdx.y, b = bh >> 4, h = bh & 15;
    int j0 = blockIdx.x * 64;
    for (int jj = 0; jj < 16; ++jj) {
        int jl = w * 16 + jj;
        int j = j0 + jl;
        float kf = 0.f, vf = 0.f;
        if (j < 2) {
            kf = nullkv[(h * 4 + 2 * j) * 64 + lane];
            vf = nullkv[(h * 4 + 2 * j + 1) * 64 + lane];
        } else if (j < 2050) {
            int n = j - 2;
            size_t base = ((size_t)b * 2048 + n) * 2048;
            kf = kv[base + h * 64 + lane];
            vf = kv[base + 1024 + h * 64 + lane];
        }
        float nrm = sqrtf(wave_sum(kf * kf));
        float kn = (j < 2050) ? kf / fmaxf(nrm, 1e-12f) * ks[lane] : 0.f;
        size_t o = ((size_t)bh * 2112 + j) * 64 + lane;
        ushort_t khv = f2bf(kn);
        Kh[o] = khv;
        Kl[o] = f2bf(kn - bf2f(khv));
        Vt[jl][lane] = f2bf(vf);
    }
    __syncthreads();
    int d = tid >> 2, seg = tid & 3;    // thread writes VT[d][j0+seg*16 .. +15]
    ushort_t buf[16];
    #pragma unroll
    for (int e = 0; e < 16; ++e) buf[e] = Vt[seg * 16 + e][d];
    size_t o = ((size_t)bh * 64 + d) * 2112 + j0 + seg * 16;
    *(bf16x8_t*)&VTh[o]     = *(const bf16x8_t*)&buf[0];
    *(bf16x8_t*)&VTh[o + 8] = *(const bf16x8_t*)&buf[8];
}

// ---------------- MFMA flash attention, static-max softmax, software-pipelined ----------------
// p = exp2((s + bias - 16)*log2e): |s|<=8, bias tail < 6 -> arg < 0 always; softmax
// is scale-invariant so no running max / rescale is needed. QK = (qh+ql)*kh + qh*kl.
// PV = ph*vh. Pipeline: Ks double-buffered (staged one iter ahead), Vs SINGLE-
// buffered (staged at END of iter it-1, made visible by mid-iter barrier B of
// iter it, after QK+exp so the drain is covered). Two barriers/iter:
//   stageK(it+1) -> QK -> exp -> [B: V(it) visible, K(it+1) drained] -> PV
//   -> [A: Vs free] -> stageV(it+1)
// LDS = Ks 32K + Vs 8K + Ps 9K = 50176 B -> 3 blocks/CU (vs 58K/2 with V dbuf).
__global__ __launch_bounds__(256, 3) void attn_mfma(const ushort_t* __restrict__ Qh,
                                                    const ushort_t* __restrict__ Ql,
                                                    const ushort_t* __restrict__ Kh,
                                                    const ushort_t* __restrict__ Kl,
                                                    const ushort_t* __restrict__ VTh,
                                                    const float* __restrict__ bias,
                                                    const int* __restrict__ mask,
                                                    ushort_t* __restrict__ aoh,
                                                    ushort_t* __restrict__ aol) {
    __shared__ ushort_t Ks[2][64 * 128];   // row j: [kh 64 | kl 64], 16 chunks swizzled
    __shared__ ushort_t Vs[64 * 64];       // row d: vh 64, 8 chunks swizzled (single buf)
    __shared__ ushort_t Ps[4][16 * 72];

    int tid = threadIdx.x;
    int w = tid >> 6, lane = tid & 63;
    int quad = lane >> 4, l15 = lane & 15;
    int rx = l15 & 7;
    int qt = 31 - blockIdx.x;           // longest blocks first (causal imbalance)
    int bh = blockIdx.y;
    int b = bh >> 4, h = bh & 15;
    int i0 = qt * 64, r0 = i0 + w * 16;
    const int nIter = qt + 2;           // j-tiles: j0 = 0,64,...,(qt+1)*64

    // --- staging: K (4 chunks) for one j-tile into given buffer ---
    auto stageK = [&](int j0, ushort_t* kd) {
        #pragma unroll
        for (int c = 0; c < 4; ++c) {        // K: 1024 chunks
            int idx = c * 256 + tid;
            int r = idx >> 4, cl = idx & 15;
            int cg = (cl & 8) | ((cl ^ (r & 7)) & 7);
            const ushort_t* g = ((cg & 8) ? Kl : Kh)
                + ((size_t)bh * 2112 + j0 + r) * 64 + (cg & 7) * 8;
            gl_lds16(g, &kd[(c * 256 + w * 64) * 8]);
        }
    };
    // --- staging: V (2 chunks) for one j-tile into the single Vs buffer ---
    auto stageV = [&](int j0) {
        #pragma unroll
        for (int c = 0; c < 2; ++c) {        // V: 512 chunks
            int idx = c * 256 + tid;
            int r = idx >> 3, cl = idx & 7;
            int cg = cl ^ (r & 7);
            const ushort_t* g = VTh + ((size_t)bh * 64 + r) * 2112 + j0 + cg * 8;
            gl_lds16(g, &Vs[(c * 256 + w * 64) * 8]);
        }
    };

    // --- register prefetch of bias for one j-tile; mask/causal/-16/log2e folded ---
    float bv_n[4][4];
    auto prefetchB = [&](int j0n) {
        #pragma unroll
        for (int jt = 0; jt < 4; ++jt) {
            int jg = j0n + jt * 16 + l15;
            int km = (jg < 2) ? 1 : (jg < 2050 ? mask[b * 2048 + jg - 2] : 0);
            #pragma unroll
            for (int reg = 0; reg < 4; ++reg) {
                int ig = r0 + quad * 4 + reg;
                float bvv = (jg >= 2 && jg < 2050)
                    ? bias[((size_t)h * 2048 + ig) * 2048 + (jg - 2)] : 0.f;
                bool ok = (km != 0) && (jg <= ig + 2);
                bv_n[jt][reg] = ok ? (bvv - 16.0f) * 1.442695041f : -1e30f;
            }
        }
    };

    // prologue: stage tile 0 (K and V) + bias prefetch, overlap Q-frag loads
    stageK(0, Ks[0]);
    stageV(0);
    prefetchB(0);

    bf16x8_t aqh[2], aql[2];
    {
        size_t qbase = ((size_t)bh * 2048 + r0 + l15) * 64 + quad * 8;
        aqh[0] = *(const bf16x8_t*)&Qh[qbase];
        aqh[1] = *(const bf16x8_t*)&Qh[qbase + 32];
        aql[0] = *(const bf16x8_t*)&Ql[qbase];
        aql[1] = *(const bf16x8_t*)&Ql[qbase + 32];
    }

    floatx4 o_acc[4];
    float l_acc[4];
    #pragma unroll
    for (int dt = 0; dt < 4; ++dt)
        #pragma unroll
        for (int v = 0; v < 4; ++v) o_acc[dt][v] = 0.f;
    #pragma unroll
    for (int r = 0; r < 4; ++r) l_acc[r] = 0.f;

    __syncthreads();                      // drains tile-0 K+V staging

    for (int it = 0; it < nIter; ++it) {
        int cur = it & 1;
        int j0 = it * 64;

        // rotate prefetched bias into current regs, then issue next K-stage/prefetch
        float bv[4][4];
        #pragma unroll
        for (int jt = 0; jt < 4; ++jt)
            #pragma unroll
            for (int reg = 0; reg < 4; ++reg) bv[jt][reg] = bv_n[jt][reg];
        if (it + 1 < nIter) {
            stageK(j0 + 64, Ks[cur ^ 1]);   // drained at barrier B (cover: QK+exp)
            prefetchB(j0 + 64);
        }
        const ushort_t* ks = Ks[cur];

        // S = Q K^T  (C-layout: row i = quad*4+reg, col j = jt*16+l15)
        floatx4 s_acc[4];
        #pragma unroll
        for (int jt = 0; jt < 4; ++jt) {
            floatx4 acc;
            #pragma unroll
            for (int v = 0; v < 4; ++v) acc[v] = 0.f;
            int r = jt * 16 + l15;
            #pragma unroll
            for (int ks2 = 0; ks2 < 2; ++ks2) {
                int cc = ks2 * 4 + quad;
                bf16x8_t kbh = *(const bf16x8_t*)&ks[(r * 16 + (cc ^ rx)) * 8];
                bf16x8_t kbl = *(const bf16x8_t*)&ks[(r * 16 + 8 + (cc ^ rx)) * 8];
                acc = __builtin_amdgcn_mfma_f32_16x16x32_bf16(aqh[ks2], kbh, acc, 0, 0, 0);
                acc = __builtin_amdgcn_mfma_f32_16x16x32_bf16(aql[ks2], kbh, acc, 0, 0, 0);
                acc = __builtin_amdgcn_mfma_f32_16x16x32_bf16(aqh[ks2], kbl, acc, 0, 0, 0);
            }
            s_acc[jt] = acc;
        }

        // p = exp2(fma(s, log2e, bv)); bv already has mask/causal/-16 folded
        #pragma unroll
        for (int jt = 0; jt < 4; ++jt) {
            #pragma unroll
            for (int reg = 0; reg < 4; ++reg) {
                float pv = exp2f(fmaf(s_acc[jt][reg], 1.442695041f, bv[jt][reg]));
                l_acc[reg] += pv;
                Ps[w][(quad * 4 + reg) * 72 + jt * 16 + l15] = f2bf(pv);
            }
        }

        // barrier B: V(it) staging (issued end of iter it-1 / prologue) visible to
        // all waves; also drains K(it+1) staging under QK+exp cover.
        __syncthreads();

        // PV: P A-frags (same-wave LDS round-trip), V B-frags from single Vs
        #pragma unroll
        for (int ks2 = 0; ks2 < 2; ++ks2) {
            bf16x8_t pf = *(const bf16x8_t*)&Ps[w][l15 * 72 + ks2 * 32 + quad * 8];
            #pragma unroll
            for (int dt = 0; dt < 4; ++dt) {
                int r = dt * 16 + l15;
                int cc = ks2 * 4 + quad;
                bf16x8_t vh = *(const bf16x8_t*)&Vs[(r * 8 + (cc ^ rx)) * 8];
                o_acc[dt] = __builtin_amdgcn_mfma_f32_16x16x32_bf16(pf, vh, o_acc[dt], 0, 0, 0);
            }
        }

        // barrier A: all waves done reading Vs -> safe to restage
        __syncthreads();
        if (it + 1 < nIter) stageV(j0 + 64);   // drained at next iter's barrier B
    }

    // reduce l over the 16 l15 lanes (lane bits 0..3), rows = quad*4+reg
    #pragma unroll
    for (int reg = 0; reg < 4; ++reg) {
        #pragma unroll
        for (int m2 = 1; m2 < 16; m2 <<= 1)
            l_acc[reg] += __shfl_xor(l_acc[reg], m2, 64);
    }
    #pragma unroll
    for (int dt = 0; dt < 4; ++dt)
        #pragma unroll
        for (int reg = 0; reg < 4; ++reg) {
            int ig = r0 + quad * 4 + reg;
            float ov = o_acc[dt][reg] / l_acc[reg];
            size_t o = ((size_t)b * 2048 + ig) * 1024 + h * 64 + dt * 16 + l15;
            ushort_t hv = f2bf(ov);
            aoh[o] = hv;
            aol[o] = f2bf(ov - bf2f(hv));
        }
}

extern "C" void kernel_launch(void* const* d_in, const int* in_sizes, int n_in,
                              void* d_out, int out_size, void* d_ws, size_t ws_size,
                              hipStream_t stream) {
    const float* x         = (const float*)d_in[0];
    const int*   mask      = (const int*)d_in[1];
    const float* attn_bias = (const float*)d_in[2];
    const float* gamma     = (const float*)d_in[3];
    const float* null_kv   = (const float*)d_in[4];
    const float* Wq        = (const float*)d_in[5];
    const float* Wkv       = (const float*)d_in[6];
    const float* q_scale   = (const float*)d_in[7];
    const float* k_scale   = (const float*)d_in[8];
    const float* Wo        = (const float*)d_in[9];

    char* ws = (char*)d_ws;
    ushort_t* xnh   = (ushort_t*)ws; ws += (size_t)4096 * 1024 * 2;
    ushort_t* xnl   = (ushort_t*)ws; ws += (size_t)4096 * 1024 * 2;
    ushort_t* xh    = (ushort_t*)ws; ws += (size_t)4096 * 1024 * 2;
    ushort_t* xl    = (ushort_t*)ws; ws += (size_t)4096 * 1024 * 2;
    ushort_t* WqTh  = (ushort_t*)ws; ws += (size_t)1024 * 1024 * 2;
    ushort_t* WqTl  = (ushort_t*)ws; ws += (size_t)1024 * 1024 * 2;
    ushort_t* WkvTh = (ushort_t*)ws; ws += (size_t)2048 * 1024 * 2;
    ushort_t* WkvTl = (ushort_t*)ws; ws += (size_t)2048 * 1024 * 2;
    ushort_t* WoTh  = (ushort_t*)ws; ws += (size_t)1024 * 1024 * 2;
    ushort_t* WoTl  = (ushort_t*)ws; ws += (size_t)1024 * 1024 * 2;
    float*    q_ws  = (float*)ws;    ws += (size_t)4096 * 1024 * 4;
    float*    kvws  = (float*)ws;    ws += (size_t)4096 * 2048 * 4;
    ushort_t* Qh    = (ushort_t*)ws; ws += (size_t)32 * 2048 * 64 * 2;
    ushort_t* Ql    = (ushort_t*)ws; ws += (size_t)32 * 2048 * 64 * 2;
    ushort_t* Kh    = (ushort_t*)ws; ws += (size_t)32 * 2112 * 64 * 2;
    ushort_t* Kl    = (ushort_t*)ws; ws += (size_t)32 * 2112 * 64 * 2;
    ushort_t* VTh   = (ushort_t*)ws; ws += (size_t)32 * 2112 * 64 * 2;
    ushort_t* aoh   = (ushort_t*)ws; ws += (size_t)4096 * 1024 * 2;
    ushort_t* aol   = (ushort_t*)ws; ws += (size_t)4096 * 1024 * 2;

    transpose_split<<<dim3(32, 32), dim3(32, 8), 0, stream>>>(Wq, WqTh, WqTl, 1024, 1024);
    transpose_split<<<dim3(64, 32), dim3(32, 8), 0, stream>>>(Wkv, WkvTh, WkvTl, 1024, 2048);
    transpose_split<<<dim3(32, 32), dim3(32, 8), 0, stream>>>(Wo, WoTh, WoTl, 1024, 1024);
    ln_split<<<4096, 256, 0, stream>>>(x, gamma, xnh, xnl, xh, xl);
    gemm_bf3<<<dim3(8, 32), 256, 0, stream>>>(xnh, xnl, WqTh, WqTl, q_ws, 4096, 1024, 1024);
    gemm_bf3<<<dim3(16, 32), 256, 0, stream>>>(xh, xl, WkvTh, WkvTl, kvws, 4096, 2048, 1024);
    l2scale_q<<<16384, 256, 0, stream>>>(q_ws, q_scale, Qh, Ql);
    build_kv<<<dim3(33, 32), 256, 0, stream>>>(kvws, null_kv, k_scale, Kh, Kl, VTh);
    attn_mfma<<<dim3(32, 32), 256, 0, stream>>>(Qh, Ql, Kh, Kl, VTh, attn_bias, mask, aoh, aol);
    gemm_bf3<<<dim3(8, 32), 256, 0, stream>>>(aoh, aol, WoTh, WoTl, (float*)d_out, 4096, 1024, 1024);
}

// Round 4
// 886.366 us; speedup vs baseline: 1.2510x; 1.0154x over previous
//
#include <hip/hip_runtime.h>
#include <math.h>

typedef unsigned short ushort_t;
typedef __attribute__((ext_vector_type(8))) short bf16x8_t;   // 8 bf16 in 4 VGPRs
typedef __attribute__((ext_vector_type(4))) float floatx4;

typedef __attribute__((address_space(3))) unsigned int lds_uint;
typedef const __attribute__((address_space(1))) unsigned int glob_uint;

__device__ inline void gl_lds16(const ushort_t* g, ushort_t* l) {
    // async global->LDS, 16B/lane; LDS dest = wave-uniform base + lane*16
    __builtin_amdgcn_global_load_lds((glob_uint*)g, (lds_uint*)l, 16, 0, 0);
}

__device__ inline float bf2f(ushort_t u) {
    return __uint_as_float(((unsigned int)u) << 16);
}
__device__ inline ushort_t f2bf(float f) {
    unsigned int u = __float_as_uint(f);
    unsigned int r = (u + 0x7fffu + ((u >> 16) & 1u)) >> 16;   // RNE
    return (ushort_t)r;
}
__device__ inline float wave_sum(float v) {
    #pragma unroll
    for (int m = 1; m < 64; m <<= 1) v += __shfl_xor(v, m, 64);
    return v;
}

// ---------------- transpose W[K][N] -> WT_h/WT_l[N][K] (fp32 -> split bf16) ----------------
__global__ __launch_bounds__(256) void transpose_split(const float* __restrict__ W,
                                                       ushort_t* __restrict__ WTh,
                                                       ushort_t* __restrict__ WTl,
                                                       int K, int N) {
    __shared__ float t[32][33];
    int n0 = blockIdx.x * 32, k0 = blockIdx.y * 32;
    int tx = threadIdx.x, ty = threadIdx.y;
    for (int i = ty; i < 32; i += 8)
        t[i][tx] = W[(size_t)(k0 + i) * N + n0 + tx];
    __syncthreads();
    for (int i = ty; i < 32; i += 8) {
        float v = t[tx][i];
        ushort_t hv = f2bf(v);
        size_t o = (size_t)(n0 + i) * K + k0 + tx;
        WTh[o] = hv;
        WTl[o] = f2bf(v - bf2f(hv));
    }
}

// ---------------- LayerNorm + split both xn and raw x into hi/lo bf16 ----------------
__global__ __launch_bounds__(256) void ln_split(const float* __restrict__ x,
                                                const float* __restrict__ gamma,
                                                ushort_t* __restrict__ xnh,
                                                ushort_t* __restrict__ xnl,
                                                ushort_t* __restrict__ xh,
                                                ushort_t* __restrict__ xl) {
    int row = blockIdx.x, tid = threadIdx.x;
    int wid = tid >> 6, lane = tid & 63;
    float v[4];
    float s1 = 0.f, s2 = 0.f;
    #pragma unroll
    for (int i = 0; i < 4; ++i) {
        v[i] = x[(size_t)row * 1024 + tid + 256 * i];
        s1 += v[i];
        s2 += v[i] * v[i];
    }
    s1 = wave_sum(s1);
    s2 = wave_sum(s2);
    __shared__ float red[8];
    if (lane == 0) { red[wid] = s1; red[4 + wid] = s2; }
    __syncthreads();
    float S1 = red[0] + red[1] + red[2] + red[3];
    float S2 = red[4] + red[5] + red[6] + red[7];
    float mu = S1 * (1.0f / 1024.0f);
    float var = S2 * (1.0f / 1024.0f) - mu * mu;
    float rs = 1.0f / sqrtf(var + 1e-5f);
    #pragma unroll
    for (int i = 0; i < 4; ++i) {
        int c = tid + 256 * i;
        size_t o = (size_t)row * 1024 + c;
        ushort_t hx = f2bf(v[i]);
        xh[o] = hx;
        xl[o] = f2bf(v[i] - bf2f(hx));
        float xnv = (v[i] - mu) * rs * gamma[c];
        ushort_t hn = f2bf(xnv);
        xnh[o] = hn;
        xnl[o] = f2bf(xnv - bf2f(hn));
    }
}

// ---------------- GEMM: C[M][N] = (Ah+Al)[M][K] * (Bh+Bl)[N][K]^T, 3-term split ----------------
// LDS rows interleave [hi 32 | lo 32] u16 chunks, XOR-swizzled (cc^(r&7)) so frag
// ds_read_b128 are conflict-free; staged via global_load_lds width=16.
// Double-buffered: stage(kt+1) issued at top of iter kt so the vmcnt(0) drain at
// the single end-of-iter barrier is covered by that iteration's MFMA work.
__global__ __launch_bounds__(256) void gemm_bf3(const ushort_t* __restrict__ Ah,
                                                const ushort_t* __restrict__ Al,
                                                const ushort_t* __restrict__ Bh,
                                                const ushort_t* __restrict__ Bl,
                                                float* __restrict__ C,
                                                int M, int N, int K) {
    __shared__ ushort_t As[2][128 * 64];
    __shared__ ushort_t Bs[2][128 * 64];
    int tid = threadIdx.x;
    int w = tid >> 6, lane = tid & 63;
    int wm = w >> 1, wn = w & 1;
    int row0 = blockIdx.y * 128, col0 = blockIdx.x * 128;
    int l15 = lane & 15, l4 = lane >> 4;
    int rx = l15 & 7;
    floatx4 acc[4][4];
    #pragma unroll
    for (int i = 0; i < 4; ++i)
        #pragma unroll
        for (int j = 0; j < 4; ++j)
            #pragma unroll
            for (int v = 0; v < 4; ++v) acc[i][j][v] = 0.f;

    auto stage = [&](int kt, int bufi) {
        #pragma unroll
        for (int c = 0; c < 4; ++c) {
            int idx = c * 256 + tid;
            int r = idx >> 3, cl = idx & 7;
            int cg = cl ^ (r & 7);                         // content chunk
            const ushort_t* ga = (cg < 4 ? Ah : Al)
                + (size_t)(row0 + r) * K + kt * 32 + (cg & 3) * 8;
            gl_lds16(ga, &As[bufi][(c * 256 + w * 64) * 8]);
            const ushort_t* gb = (cg < 4 ? Bh : Bl)
                + (size_t)(col0 + r) * K + kt * 32 + (cg & 3) * 8;
            gl_lds16(gb, &Bs[bufi][(c * 256 + w * 64) * 8]);
        }
    };

    int nk = K >> 5;
    stage(0, 0);
    __syncthreads();                       // drains tile-0 staging
    for (int kt = 0; kt < nk; ++kt) {
        int cur = kt & 1;
        if (kt + 1 < nk) stage(kt + 1, cur ^ 1);   // latency hidden under this iter
        bf16x8_t af_h[4], af_l[4], bf_h[4], bf_l[4];
        #pragma unroll
        for (int mi = 0; mi < 4; ++mi) {
            int r = wm * 64 + mi * 16 + l15;
            af_h[mi] = *(const bf16x8_t*)&As[cur][(r * 8 + (l4 ^ rx)) * 8];
            af_l[mi] = *(const bf16x8_t*)&As[cur][(r * 8 + ((4 + l4) ^ rx)) * 8];
        }
        #pragma unroll
        for (int ni = 0; ni < 4; ++ni) {
            int r = wn * 64 + ni * 16 + l15;
            bf_h[ni] = *(const bf16x8_t*)&Bs[cur][(r * 8 + (l4 ^ rx)) * 8];
            bf_l[ni] = *(const bf16x8_t*)&Bs[cur][(r * 8 + ((4 + l4) ^ rx)) * 8];
        }
        #pragma unroll
        for (int mi = 0; mi < 4; ++mi)
            #pragma unroll
            for (int ni = 0; ni < 4; ++ni) {
                acc[mi][ni] = __builtin_amdgcn_mfma_f32_16x16x32_bf16(
                    af_h[mi], bf_h[ni], acc[mi][ni], 0, 0, 0);
                acc[mi][ni] = __builtin_amdgcn_mfma_f32_16x16x32_bf16(
                    af_h[mi], bf_l[ni], acc[mi][ni], 0, 0, 0);
                acc[mi][ni] = __builtin_amdgcn_mfma_f32_16x16x32_bf16(
                    af_l[mi], bf_h[ni], acc[mi][ni], 0, 0, 0);
            }
        __syncthreads();       // next buf staged AND protects cur for overwrite
    }
    #pragma unroll
    for (int mi = 0; mi < 4; ++mi)
        #pragma unroll
        for (int ni = 0; ni < 4; ++ni)
            #pragma unroll
            for (int v = 0; v < 4; ++v) {
                int rr = row0 + wm * 64 + mi * 16 + l4 * 4 + v;
                int cc = col0 + wn * 64 + ni * 16 + l15;
                C[(size_t)rr * N + cc] = acc[mi][ni][v];
            }
}

// ---------------- q: l2norm * q_scale * 8 -> split bf16 [bh][2048][64] ----------------
__global__ __launch_bounds__(256) void l2scale_q(const float* __restrict__ q,
                                                 const float* __restrict__ qs,
                                                 ushort_t* __restrict__ Qh,
                                                 ushort_t* __restrict__ Ql) {
    int rid = blockIdx.x * 4 + (threadIdx.x >> 6);
    int lane = threadIdx.x & 63;
    int h = rid & 15, n = (rid >> 4) & 2047, b = rid >> 15;
    float v = q[(size_t)rid * 64 + lane];
    float nrm = sqrtf(wave_sum(v * v));
    float qn = v / fmaxf(nrm, 1e-12f) * qs[lane] * 8.0f;
    size_t o = (((size_t)(b * 16 + h)) * 2048 + n) * 64 + lane;
    ushort_t hv = f2bf(qn);
    Qh[o] = hv;
    Ql[o] = f2bf(qn - bf2f(hv));
}

// ---------------- build K split [bh][2112][64], V^T hi [bh][64][2112] (coalesced) ----------------
__global__ __launch_bounds__(256) void build_kv(const float* __restrict__ kv,
                                                const float* __restrict__ nullkv,
                                                const float* __restrict__ ks,
                                                ushort_t* __restrict__ Kh,
                                                ushort_t* __restrict__ Kl,
                                                ushort_t* __restrict__ VTh) {
    __shared__ ushort_t Vt[64][72];     // [j][d]
    int tid = threadIdx.x;
    int w = tid >> 6, lane = tid & 63;
    int bh = blockIdx.y, b = bh >> 4, h = bh & 15;
    int j0 = blockIdx.x * 64;
    for (int jj = 0; jj < 16; ++jj) {
        int jl = w * 16 + jj;
        int j = j0 + jl;
        float kf = 0.f, vf = 0.f;
        if (j < 2) {
            kf = nullkv[(h * 4 + 2 * j) * 64 + lane];
            vf = nullkv[(h * 4 + 2 * j + 1) * 64 + lane];
        } else if (j < 2050) {
            int n = j - 2;
            size_t base = ((size_t)b * 2048 + n) * 2048;
            kf = kv[base + h * 64 + lane];
            vf = kv[base + 1024 + h * 64 + lane];
        }
        float nrm = sqrtf(wave_sum(kf * kf));
        float kn = (j < 2050) ? kf / fmaxf(nrm, 1e-12f) * ks[lane] : 0.f;
        size_t o = ((size_t)bh * 2112 + j) * 64 + lane;
        ushort_t khv = f2bf(kn);
        Kh[o] = khv;
        Kl[o] = f2bf(kn - bf2f(khv));
        Vt[jl][lane] = f2bf(vf);
    }
    __syncthreads();
    int d = tid >> 2, seg = tid & 3;    // thread writes VT[d][j0+seg*16 .. +15]
    ushort_t buf[16];
    #pragma unroll
    for (int e = 0; e < 16; ++e) buf[e] = Vt[seg * 16 + e][d];
    size_t o = ((size_t)bh * 64 + d) * 2112 + j0 + seg * 16;
    *(bf16x8_t*)&VTh[o]     = *(const bf16x8_t*)&buf[0];
    *(bf16x8_t*)&VTh[o + 8] = *(const bf16x8_t*)&buf[8];
}

// ---------------- MFMA flash attention, static-max softmax, software-pipelined ----------------
// R1-proven schedule: K AND V double-buffered in LDS, both staged at the TOP of
// iter it for it+1, ONE barrier per iter -> every staging op gets a full
// iteration (QK+exp+PV) of latency cover before its vmcnt(0) drain. (R2/R3
// variants that shortened this cover regressed 2-3x; do not shorten it.)
// p = exp2((s + bias - 16)*log2e): |s|<=8, bias tail < 6 -> arg < 0 always;
// softmax is scale-invariant so no running max / rescale needed.
// QK = (qh+ql)*kh + qh*kl. PV = ph*vh.
// blockIdx.y remap: h = y>>1, b = y&1 so the two batches of the same head are
// dispatch-adjacent and share their identical bias slice in L2/L3.
__global__ __launch_bounds__(256) void attn_mfma(const ushort_t* __restrict__ Qh,
                                                 const ushort_t* __restrict__ Ql,
                                                 const ushort_t* __restrict__ Kh,
                                                 const ushort_t* __restrict__ Kl,
                                                 const ushort_t* __restrict__ VTh,
                                                 const float* __restrict__ bias,
                                                 const int* __restrict__ mask,
                                                 ushort_t* __restrict__ aoh,
                                                 ushort_t* __restrict__ aol) {
    __shared__ ushort_t Ks[2][64 * 128];   // row j: [kh 64 | kl 64], 16 chunks swizzled
    __shared__ ushort_t Vs[2][64 * 64];    // row d: vh 64, 8 chunks swizzled
    __shared__ ushort_t Ps[4][16 * 72];

    int tid = threadIdx.x;
    int w = tid >> 6, lane = tid & 63;
    int quad = lane >> 4, l15 = lane & 15;
    int rx = l15 & 7;
    int qt = 31 - blockIdx.x;           // longest blocks first (causal imbalance)
    int yy = blockIdx.y;
    int h = yy >> 1, b = yy & 1;        // adjacent y-blocks share the bias slice
    int bh = b * 16 + h;                // storage index for Q/K/V/out
    int i0 = qt * 64, r0 = i0 + w * 16;
    const int nIter = qt + 2;           // j-tiles: j0 = 0,64,...,(qt+1)*64

    // --- staging: K (4 chunks) + V (2 chunks) for one j-tile into given buffers ---
    auto stage = [&](int j0, ushort_t* kd, ushort_t* vd) {
        #pragma unroll
        for (int c = 0; c < 4; ++c) {        // K: 1024 chunks
            int idx = c * 256 + tid;
            int r = idx >> 4, cl = idx & 15;
            int cg = (cl & 8) | ((cl ^ (r & 7)) & 7);
            const ushort_t* g = ((cg & 8) ? Kl : Kh)
                + ((size_t)bh * 2112 + j0 + r) * 64 + (cg & 7) * 8;
            gl_lds16(g, &kd[(c * 256 + w * 64) * 8]);
        }
        #pragma unroll
        for (int c = 0; c < 2; ++c) {        // V: 512 chunks
            int idx = c * 256 + tid;
            int r = idx >> 3, cl = idx & 7;
            int cg = cl ^ (r & 7);
            const ushort_t* g = VTh + ((size_t)bh * 64 + r) * 2112 + j0 + cg * 8;
            gl_lds16(g, &vd[(c * 256 + w * 64) * 8]);
        }
    };

    // --- register prefetch of bias for one j-tile; mask/causal/-16/log2e folded ---
    float bv_n[4][4];
    auto prefetchB = [&](int j0n) {
        #pragma unroll
        for (int jt = 0; jt < 4; ++jt) {
            int jg = j0n + jt * 16 + l15;
            int km = (jg < 2) ? 1 : (jg < 2050 ? mask[b * 2048 + jg - 2] : 0);
            #pragma unroll
            for (int reg = 0; reg < 4; ++reg) {
                int ig = r0 + quad * 4 + reg;
                float bvv = (jg >= 2 && jg < 2050)
                    ? bias[((size_t)h * 2048 + ig) * 2048 + (jg - 2)] : 0.f;
                bool ok = (km != 0) && (jg <= ig + 2);
                bv_n[jt][reg] = ok ? (bvv - 16.0f) * 1.442695041f : -1e30f;
            }
        }
    };

    // issue tile-0 staging + prefetch first, then overlap Q-frag loads with it
    stage(0, Ks[0], Vs[0]);
    prefetchB(0);

    bf16x8_t aqh[2], aql[2];
    {
        size_t qbase = ((size_t)bh * 2048 + r0 + l15) * 64 + quad * 8;
        aqh[0] = *(const bf16x8_t*)&Qh[qbase];
        aqh[1] = *(const bf16x8_t*)&Qh[qbase + 32];
        aql[0] = *(const bf16x8_t*)&Ql[qbase];
        aql[1] = *(const bf16x8_t*)&Ql[qbase + 32];
    }

    floatx4 o_acc[4];
    float l_acc[4];
    #pragma unroll
    for (int dt = 0; dt < 4; ++dt)
        #pragma unroll
        for (int v = 0; v < 4; ++v) o_acc[dt][v] = 0.f;
    #pragma unroll
    for (int r = 0; r < 4; ++r) l_acc[r] = 0.f;

    __syncthreads();                      // drains tile-0 staging (vmcnt 0)

    for (int it = 0; it < nIter; ++it) {
        int cur = it & 1;
        int j0 = it * 64;

        // rotate prefetched bias into current regs, then issue next prefetch/stage
        float bv[4][4];
        #pragma unroll
        for (int jt = 0; jt < 4; ++jt)
            #pragma unroll
            for (int reg = 0; reg < 4; ++reg) bv[jt][reg] = bv_n[jt][reg];
        if (it + 1 < nIter) {
            stage(j0 + 64, Ks[cur ^ 1], Vs[cur ^ 1]);   // full-iter latency cover
            prefetchB(j0 + 64);
        }
        const ushort_t* ks = Ks[cur];
        const ushort_t* vs = Vs[cur];

        // S = Q K^T  (C-layout: row i = quad*4+reg, col j = jt*16+l15)
        floatx4 s_acc[4];
        #pragma unroll
        for (int jt = 0; jt < 4; ++jt) {
            floatx4 acc;
            #pragma unroll
            for (int v = 0; v < 4; ++v) acc[v] = 0.f;
            int r = jt * 16 + l15;
            #pragma unroll
            for (int ks2 = 0; ks2 < 2; ++ks2) {
                int cc = ks2 * 4 + quad;
                bf16x8_t kbh = *(const bf16x8_t*)&ks[(r * 16 + (cc ^ rx)) * 8];
                bf16x8_t kbl = *(const bf16x8_t*)&ks[(r * 16 + 8 + (cc ^ rx)) * 8];
                acc = __builtin_amdgcn_mfma_f32_16x16x32_bf16(aqh[ks2], kbh, acc, 0, 0, 0);
                acc = __builtin_amdgcn_mfma_f32_16x16x32_bf16(aql[ks2], kbh, acc, 0, 0, 0);
                acc = __builtin_amdgcn_mfma_f32_16x16x32_bf16(aqh[ks2], kbl, acc, 0, 0, 0);
            }
            s_acc[jt] = acc;
        }

        // p = exp2(fma(s, log2e, bv)); bv already has mask/causal/-16 folded
        #pragma unroll
        for (int jt = 0; jt < 4; ++jt) {
            #pragma unroll
            for (int reg = 0; reg < 4; ++reg) {
                float pv = exp2f(fmaf(s_acc[jt][reg], 1.442695041f, bv[jt][reg]));
                l_acc[reg] += pv;
                Ps[w][(quad * 4 + reg) * 72 + jt * 16 + l15] = f2bf(pv);
            }
        }

        // PV: P A-frags (same-wave LDS round-trip, no barrier needed)
        #pragma unroll
        for (int ks2 = 0; ks2 < 2; ++ks2) {
            bf16x8_t pf = *(const bf16x8_t*)&Ps[w][l15 * 72 + ks2 * 32 + quad * 8];
            #pragma unroll
            for (int dt = 0; dt < 4; ++dt) {
                int r = dt * 16 + l15;
                int cc = ks2 * 4 + quad;
                bf16x8_t vh = *(const bf16x8_t*)&vs[(r * 8 + (cc ^ rx)) * 8];
                o_acc[dt] = __builtin_amdgcn_mfma_f32_16x16x32_bf16(pf, vh, o_acc[dt], 0, 0, 0);
            }
        }

        // single barrier: drains next-tile staging AND protects buffer reuse
        __syncthreads();
    }

    // reduce l over the 16 l15 lanes (lane bits 0..3), rows = quad*4+reg
    #pragma unroll
    for (int reg = 0; reg < 4; ++reg) {
        #pragma unroll
        for (int m2 = 1; m2 < 16; m2 <<= 1)
            l_acc[reg] += __shfl_xor(l_acc[reg], m2, 64);
    }
    #pragma unroll
    for (int dt = 0; dt < 4; ++dt)
        #pragma unroll
        for (int reg = 0; reg < 4; ++reg) {
            int ig = r0 + quad * 4 + reg;
            float ov = o_acc[dt][reg] / l_acc[reg];
            size_t o = ((size_t)b * 2048 + ig) * 1024 + h * 64 + dt * 16 + l15;
            ushort_t hv = f2bf(ov);
            aoh[o] = hv;
            aol[o] = f2bf(ov - bf2f(hv));
        }
}

extern "C" void kernel_launch(void* const* d_in, const int* in_sizes, int n_in,
                              void* d_out, int out_size, void* d_ws, size_t ws_size,
                              hipStream_t stream) {
    const float* x         = (const float*)d_in[0];
    const int*   mask      = (const int*)d_in[1];
    const float* attn_bias = (const float*)d_in[2];
    const float* gamma     = (const float*)d_in[3];
    const float* null_kv   = (const float*)d_in[4];
    const float* Wq        = (const float*)d_in[5];
    const float* Wkv       = (const float*)d_in[6];
    const float* q_scale   = (const float*)d_in[7];
    const float* k_scale   = (const float*)d_in[8];
    const float* Wo        = (const float*)d_in[9];

    char* ws = (char*)d_ws;
    ushort_t* xnh   = (ushort_t*)ws; ws += (size_t)4096 * 1024 * 2;
    ushort_t* xnl   = (ushort_t*)ws; ws += (size_t)4096 * 1024 * 2;
    ushort_t* xh    = (ushort_t*)ws; ws += (size_t)4096 * 1024 * 2;
    ushort_t* xl    = (ushort_t*)ws; ws += (size_t)4096 * 1024 * 2;
    ushort_t* WqTh  = (ushort_t*)ws; ws += (size_t)1024 * 1024 * 2;
    ushort_t* WqTl  = (ushort_t*)ws; ws += (size_t)1024 * 1024 * 2;
    ushort_t* WkvTh = (ushort_t*)ws; ws += (size_t)2048 * 1024 * 2;
    ushort_t* WkvTl = (ushort_t*)ws; ws += (size_t)2048 * 1024 * 2;
    ushort_t* WoTh  = (ushort_t*)ws; ws += (size_t)1024 * 1024 * 2;
    ushort_t* WoTl  = (ushort_t*)ws; ws += (size_t)1024 * 1024 * 2;
    float*    q_ws  = (float*)ws;    ws += (size_t)4096 * 1024 * 4;
    float*    kvws  = (float*)ws;    ws += (size_t)4096 * 2048 * 4;
    ushort_t* Qh    = (ushort_t*)ws; ws += (size_t)32 * 2048 * 64 * 2;
    ushort_t* Ql    = (ushort_t*)ws; ws += (size_t)32 * 2048 * 64 * 2;
    ushort_t* Kh    = (ushort_t*)ws; ws += (size_t)32 * 2112 * 64 * 2;
    ushort_t* Kl    = (ushort_t*)ws; ws += (size_t)32 * 2112 * 64 * 2;
    ushort_t* VTh   = (ushort_t*)ws; ws += (size_t)32 * 2112 * 64 * 2;
    ushort_t* aoh   = (ushort_t*)ws; ws += (size_t)4096 * 1024 * 2;
    ushort_t* aol   = (ushort_t*)ws; ws += (size_t)4096 * 1024 * 2;

    transpose_split<<<dim3(32, 32), dim3(32, 8), 0, stream>>>(Wq, WqTh, WqTl, 1024, 1024);
    transpose_split<<<dim3(64, 32), dim3(32, 8), 0, stream>>>(Wkv, WkvTh, WkvTl, 1024, 2048);
    transpose_split<<<dim3(32, 32), dim3(32, 8), 0, stream>>>(Wo, WoTh, WoTl, 1024, 1024);
    ln_split<<<4096, 256, 0, stream>>>(x, gamma, xnh, xnl, xh, xl);
    gemm_bf3<<<dim3(8, 32), 256, 0, stream>>>(xnh, xnl, WqTh, WqTl, q_ws, 4096, 1024, 1024);
    gemm_bf3<<<dim3(16, 32), 256, 0, stream>>>(xh, xl, WkvTh, WkvTl, kvws, 4096, 2048, 1024);
    l2scale_q<<<16384, 256, 0, stream>>>(q_ws, q_scale, Qh, Ql);
    build_kv<<<dim3(33, 32), 256, 0, stream>>>(kvws, null_kv, k_scale, Kh, Kl, VTh);
    attn_mfma<<<dim3(32, 32), 256, 0, stream>>>(Qh, Ql, Kh, Kl, VTh, attn_bias, mask, aoh, aol);
    gemm_bf3<<<dim3(8, 32), 256, 0, stream>>>(aoh, aol, WoTh, WoTl, (float*)d_out, 4096, 1024, 1024);
}

// Round 5
// 657.725 us; speedup vs baseline: 1.6859x; 1.3476x over previous
//
#include <hip/hip_runtime.h>
#include <math.h>

typedef unsigned short ushort_t;
typedef __attribute__((ext_vector_type(8))) short bf16x8_t;   // 8 bf16 in 4 VGPRs
typedef __attribute__((ext_vector_type(4))) float floatx4;

typedef __attribute__((address_space(3))) unsigned int lds_uint;
typedef const __attribute__((address_space(1))) unsigned int glob_uint;

__device__ inline void gl_lds16(const ushort_t* g, ushort_t* l) {
    // async global->LDS, 16B/lane; LDS dest = wave-uniform base + lane*16
    __builtin_amdgcn_global_load_lds((glob_uint*)g, (lds_uint*)l, 16, 0, 0);
}

__device__ inline float bf2f(ushort_t u) {
    return __uint_as_float(((unsigned int)u) << 16);
}
__device__ inline ushort_t f2bf(float f) {
    unsigned int u = __float_as_uint(f);
    unsigned int r = (u + 0x7fffu + ((u >> 16) & 1u)) >> 16;   // RNE
    return (ushort_t)r;
}
__device__ inline float wave_sum(float v) {
    #pragma unroll
    for (int m = 1; m < 64; m <<= 1) v += __shfl_xor(v, m, 64);
    return v;
}

// ---------------- transpose W[K][N] -> WT_h/WT_l[N][K] (fp32 -> split bf16) ----------------
__global__ __launch_bounds__(256) void transpose_split(const float* __restrict__ W,
                                                       ushort_t* __restrict__ WTh,
                                                       ushort_t* __restrict__ WTl,
                                                       int K, int N) {
    __shared__ float t[32][33];
    int n0 = blockIdx.x * 32, k0 = blockIdx.y * 32;
    int tx = threadIdx.x, ty = threadIdx.y;
    for (int i = ty; i < 32; i += 8)
        t[i][tx] = W[(size_t)(k0 + i) * N + n0 + tx];
    __syncthreads();
    for (int i = ty; i < 32; i += 8) {
        float v = t[tx][i];
        ushort_t hv = f2bf(v);
        size_t o = (size_t)(n0 + i) * K + k0 + tx;
        WTh[o] = hv;
        WTl[o] = f2bf(v - bf2f(hv));
    }
}

// ---------------- LayerNorm + split both xn and raw x into hi/lo bf16 ----------------
__global__ __launch_bounds__(256) void ln_split(const float* __restrict__ x,
                                                const float* __restrict__ gamma,
                                                ushort_t* __restrict__ xnh,
                                                ushort_t* __restrict__ xnl,
                                                ushort_t* __restrict__ xh,
                                                ushort_t* __restrict__ xl) {
    int row = blockIdx.x, tid = threadIdx.x;
    int wid = tid >> 6, lane = tid & 63;
    float v[4];
    float s1 = 0.f, s2 = 0.f;
    #pragma unroll
    for (int i = 0; i < 4; ++i) {
        v[i] = x[(size_t)row * 1024 + tid + 256 * i];
        s1 += v[i];
        s2 += v[i] * v[i];
    }
    s1 = wave_sum(s1);
    s2 = wave_sum(s2);
    __shared__ float red[8];
    if (lane == 0) { red[wid] = s1; red[4 + wid] = s2; }
    __syncthreads();
    float S1 = red[0] + red[1] + red[2] + red[3];
    float S2 = red[4] + red[5] + red[6] + red[7];
    float mu = S1 * (1.0f / 1024.0f);
    float var = S2 * (1.0f / 1024.0f) - mu * mu;
    float rs = 1.0f / sqrtf(var + 1e-5f);
    #pragma unroll
    for (int i = 0; i < 4; ++i) {
        int c = tid + 256 * i;
        size_t o = (size_t)row * 1024 + c;
        ushort_t hx = f2bf(v[i]);
        xh[o] = hx;
        xl[o] = f2bf(v[i] - bf2f(hx));
        float xnv = (v[i] - mu) * rs * gamma[c];
        ushort_t hn = f2bf(xnv);
        xnh[o] = hn;
        xnl[o] = f2bf(xnv - bf2f(hn));
    }
}

// ---------------- GEMM 128x128: C = (Ah+Al)(Bh+Bl)^T, 3-term split, dbuf ----------------
__global__ __launch_bounds__(256) void gemm_bf3(const ushort_t* __restrict__ Ah,
                                                const ushort_t* __restrict__ Al,
                                                const ushort_t* __restrict__ Bh,
                                                const ushort_t* __restrict__ Bl,
                                                float* __restrict__ C,
                                                int M, int N, int K) {
    __shared__ ushort_t As[2][128 * 64];
    __shared__ ushort_t Bs[2][128 * 64];
    int tid = threadIdx.x;
    int w = tid >> 6, lane = tid & 63;
    int wm = w >> 1, wn = w & 1;
    int row0 = blockIdx.y * 128, col0 = blockIdx.x * 128;
    int l15 = lane & 15, l4 = lane >> 4;
    int rx = l15 & 7;
    floatx4 acc[4][4];
    #pragma unroll
    for (int i = 0; i < 4; ++i)
        #pragma unroll
        for (int j = 0; j < 4; ++j)
            #pragma unroll
            for (int v = 0; v < 4; ++v) acc[i][j][v] = 0.f;

    auto stage = [&](int kt, int bufi) {
        #pragma unroll
        for (int c = 0; c < 4; ++c) {
            int idx = c * 256 + tid;
            int r = idx >> 3, cl = idx & 7;
            int cg = cl ^ (r & 7);                         // content chunk
            const ushort_t* ga = (cg < 4 ? Ah : Al)
                + (size_t)(row0 + r) * K + kt * 32 + (cg & 3) * 8;
            gl_lds16(ga, &As[bufi][(c * 256 + w * 64) * 8]);
            const ushort_t* gb = (cg < 4 ? Bh : Bl)
                + (size_t)(col0 + r) * K + kt * 32 + (cg & 3) * 8;
            gl_lds16(gb, &Bs[bufi][(c * 256 + w * 64) * 8]);
        }
    };

    int nk = K >> 5;
    stage(0, 0);
    __syncthreads();                       // drains tile-0 staging
    for (int kt = 0; kt < nk; ++kt) {
        int cur = kt & 1;
        if (kt + 1 < nk) stage(kt + 1, cur ^ 1);   // latency hidden under this iter
        bf16x8_t af_h[4], af_l[4], bf_h[4], bf_l[4];
        #pragma unroll
        for (int mi = 0; mi < 4; ++mi) {
            int r = wm * 64 + mi * 16 + l15;
            af_h[mi] = *(const bf16x8_t*)&As[cur][(r * 8 + (l4 ^ rx)) * 8];
            af_l[mi] = *(const bf16x8_t*)&As[cur][(r * 8 + ((4 + l4) ^ rx)) * 8];
        }
        #pragma unroll
        for (int ni = 0; ni < 4; ++ni) {
            int r = wn * 64 + ni * 16 + l15;
            bf_h[ni] = *(const bf16x8_t*)&Bs[cur][(r * 8 + (l4 ^ rx)) * 8];
            bf_l[ni] = *(const bf16x8_t*)&Bs[cur][(r * 8 + ((4 + l4) ^ rx)) * 8];
        }
        #pragma unroll
        for (int mi = 0; mi < 4; ++mi)
            #pragma unroll
            for (int ni = 0; ni < 4; ++ni) {
                acc[mi][ni] = __builtin_amdgcn_mfma_f32_16x16x32_bf16(
                    af_h[mi], bf_h[ni], acc[mi][ni], 0, 0, 0);
                acc[mi][ni] = __builtin_amdgcn_mfma_f32_16x16x32_bf16(
                    af_h[mi], bf_l[ni], acc[mi][ni], 0, 0, 0);
                acc[mi][ni] = __builtin_amdgcn_mfma_f32_16x16x32_bf16(
                    af_l[mi], bf_h[ni], acc[mi][ni], 0, 0, 0);
            }
        __syncthreads();       // next buf staged AND protects cur for overwrite
    }
    #pragma unroll
    for (int mi = 0; mi < 4; ++mi)
        #pragma unroll
        for (int ni = 0; ni < 4; ++ni)
            #pragma unroll
            for (int v = 0; v < 4; ++v) {
                int rr = row0 + wm * 64 + mi * 16 + l4 * 4 + v;
                int cc = col0 + wn * 64 + ni * 16 + l15;
                C[(size_t)rr * N + cc] = acc[mi][ni][v];
            }
}

// ---------------- GEMM 128x64 tile variant: for N=1024 outputs (Q / O proj). ----------------
// Same staging/swizzle/frag patterns as gemm_bf3, but BN=64 so the grid doubles
// (16x32 = 512 blocks = 2 blocks/CU instead of 1) -> cross-block latency hiding.
// 4 waves stacked in M (wave = 32 M-rows x 64 N-cols). LDS 48 KB.
__global__ __launch_bounds__(256) void gemm_bf3_n64(const ushort_t* __restrict__ Ah,
                                                    const ushort_t* __restrict__ Al,
                                                    const ushort_t* __restrict__ Bh,
                                                    const ushort_t* __restrict__ Bl,
                                                    float* __restrict__ C,
                                                    int M, int N, int K) {
    __shared__ ushort_t As[2][128 * 64];
    __shared__ ushort_t Bs[2][64 * 64];
    int tid = threadIdx.x;
    int w = tid >> 6, lane = tid & 63;
    int row0 = blockIdx.y * 128, col0 = blockIdx.x * 64;
    int l15 = lane & 15, l4 = lane >> 4;
    int rx = l15 & 7;
    floatx4 acc[2][4];
    #pragma unroll
    for (int i = 0; i < 2; ++i)
        #pragma unroll
        for (int j = 0; j < 4; ++j)
            #pragma unroll
            for (int v = 0; v < 4; ++v) acc[i][j][v] = 0.f;

    auto stage = [&](int kt, int bufi) {
        #pragma unroll
        for (int c = 0; c < 4; ++c) {          // A: 1024 chunks
            int idx = c * 256 + tid;
            int r = idx >> 3, cl = idx & 7;
            int cg = cl ^ (r & 7);
            const ushort_t* ga = (cg < 4 ? Ah : Al)
                + (size_t)(row0 + r) * K + kt * 32 + (cg & 3) * 8;
            gl_lds16(ga, &As[bufi][(c * 256 + w * 64) * 8]);
        }
        #pragma unroll
        for (int c = 0; c < 2; ++c) {          // B: 512 chunks
            int idx = c * 256 + tid;
            int r = idx >> 3, cl = idx & 7;
            int cg = cl ^ (r & 7);
            const ushort_t* gb = (cg < 4 ? Bh : Bl)
                + (size_t)(col0 + r) * K + kt * 32 + (cg & 3) * 8;
            gl_lds16(gb, &Bs[bufi][(c * 256 + w * 64) * 8]);
        }
    };

    int nk = K >> 5;
    stage(0, 0);
    __syncthreads();
    for (int kt = 0; kt < nk; ++kt) {
        int cur = kt & 1;
        if (kt + 1 < nk) stage(kt + 1, cur ^ 1);
        bf16x8_t af_h[2], af_l[2], bf_h[4], bf_l[4];
        #pragma unroll
        for (int mi = 0; mi < 2; ++mi) {
            int r = w * 32 + mi * 16 + l15;
            af_h[mi] = *(const bf16x8_t*)&As[cur][(r * 8 + (l4 ^ rx)) * 8];
            af_l[mi] = *(const bf16x8_t*)&As[cur][(r * 8 + ((4 + l4) ^ rx)) * 8];
        }
        #pragma unroll
        for (int ni = 0; ni < 4; ++ni) {
            int r = ni * 16 + l15;
            bf_h[ni] = *(const bf16x8_t*)&Bs[cur][(r * 8 + (l4 ^ rx)) * 8];
            bf_l[ni] = *(const bf16x8_t*)&Bs[cur][(r * 8 + ((4 + l4) ^ rx)) * 8];
        }
        #pragma unroll
        for (int mi = 0; mi < 2; ++mi)
            #pragma unroll
            for (int ni = 0; ni < 4; ++ni) {
                acc[mi][ni] = __builtin_amdgcn_mfma_f32_16x16x32_bf16(
                    af_h[mi], bf_h[ni], acc[mi][ni], 0, 0, 0);
                acc[mi][ni] = __builtin_amdgcn_mfma_f32_16x16x32_bf16(
                    af_h[mi], bf_l[ni], acc[mi][ni], 0, 0, 0);
                acc[mi][ni] = __builtin_amdgcn_mfma_f32_16x16x32_bf16(
                    af_l[mi], bf_h[ni], acc[mi][ni], 0, 0, 0);
            }
        __syncthreads();
    }
    #pragma unroll
    for (int mi = 0; mi < 2; ++mi)
        #pragma unroll
        for (int ni = 0; ni < 4; ++ni)
            #pragma unroll
            for (int v = 0; v < 4; ++v) {
                int rr = row0 + w * 32 + mi * 16 + l4 * 4 + v;
                int cc = col0 + ni * 16 + l15;
                C[(size_t)rr * N + cc] = acc[mi][ni][v];
            }
}

// ---------------- q: l2norm * q_scale * 8 -> split bf16 [bh][2048][64] ----------------
__global__ __launch_bounds__(256) void l2scale_q(const float* __restrict__ q,
                                                 const float* __restrict__ qs,
                                                 ushort_t* __restrict__ Qh,
                                                 ushort_t* __restrict__ Ql) {
    int rid = blockIdx.x * 4 + (threadIdx.x >> 6);
    int lane = threadIdx.x & 63;
    int h = rid & 15, n = (rid >> 4) & 2047, b = rid >> 15;
    float v = q[(size_t)rid * 64 + lane];
    float nrm = sqrtf(wave_sum(v * v));
    float qn = v / fmaxf(nrm, 1e-12f) * qs[lane] * 8.0f;
    size_t o = (((size_t)(b * 16 + h)) * 2048 + n) * 64 + lane;
    ushort_t hv = f2bf(qn);
    Qh[o] = hv;
    Ql[o] = f2bf(qn - bf2f(hv));
}

// ---------------- build K split [bh][2112][64], V^T hi [bh][64][2112] (coalesced) ----------------
__global__ __launch_bounds__(256) void build_kv(const float* __restrict__ kv,
                                                const float* __restrict__ nullkv,
                                                const float* __restrict__ ks,
                                                ushort_t* __restrict__ Kh,
                                                ushort_t* __restrict__ Kl,
                                                ushort_t* __restrict__ VTh) {
    __shared__ ushort_t Vt[64][72];     // [j][d]
    int tid = threadIdx.x;
    int w = tid >> 6, lane = tid & 63;
    int bh = blockIdx.y, b = bh >> 4, h = bh & 15;
    int j0 = blockIdx.x * 64;
    for (int jj = 0; jj < 16; ++jj) {
        int jl = w * 16 + jj;
        int j = j0 + jl;
        float kf = 0.f, vf = 0.f;
        if (j < 2) {
            kf = nullkv[(h * 4 + 2 * j) * 64 + lane];
            vf = nullkv[(h * 4 + 2 * j + 1) * 64 + lane];
        } else if (j < 2050) {
            int n = j - 2;
            size_t base = ((size_t)b * 2048 + n) * 2048;
            kf = kv[base + h * 64 + lane];
            vf = kv[base + 1024 + h * 64 + lane];
        }
        float nrm = sqrtf(wave_sum(kf * kf));
        float kn = (j < 2050) ? kf / fmaxf(nrm, 1e-12f) * ks[lane] : 0.f;
        size_t o = ((size_t)bh * 2112 + j) * 64 + lane;
        ushort_t khv = f2bf(kn);
        Kh[o] = khv;
        Kl[o] = f2bf(kn - bf2f(khv));
        Vt[jl][lane] = f2bf(vf);
    }
    __syncthreads();
    int d = tid >> 2, seg = tid & 3;    // thread writes VT[d][j0+seg*16 .. +15]
    ushort_t buf[16];
    #pragma unroll
    for (int e = 0; e < 16; ++e) buf[e] = Vt[seg * 16 + e][d];
    size_t o = ((size_t)bh * 64 + d) * 2112 + j0 + seg * 16;
    *(bf16x8_t*)&VTh[o]     = *(const bf16x8_t*)&buf[0];
    *(bf16x8_t*)&VTh[o + 8] = *(const bf16x8_t*)&buf[8];
}

// ---------------- MFMA flash attention — EXACT R1 kernel (measured 186 us) ----------------
// p = exp(s + bias - 16): |s|<=8, bias tail < 6 -> arg < 0 always; softmax is
// scale-invariant so no running max / rescale is needed. QK = (qh+ql)*kh + qh*kl.
// PV = ph*vh. Pipelining: K/V double-buffered in LDS, stage(it+1) issued at the
// TOP of iter it so the vmcnt(0) drain at the single end-of-iter barrier is
// covered by the whole iteration's compute. Bias/mask for iter it+1 prefetched
// into registers one iteration ahead (HBM latency off the exp critical path).
// DO NOT: fold mask/-16/log2e into the prefetched bias, remap blockIdx.y, or
// shorten staging cover — each variant measured 2x slower (R2/R3/R4).
__global__ __launch_bounds__(256) void attn_mfma(const ushort_t* __restrict__ Qh,
                                                 const ushort_t* __restrict__ Ql,
                                                 const ushort_t* __restrict__ Kh,
                                                 const ushort_t* __restrict__ Kl,
                                                 const ushort_t* __restrict__ VTh,
                                                 const float* __restrict__ bias,
                                                 const int* __restrict__ mask,
                                                 ushort_t* __restrict__ aoh,
                                                 ushort_t* __restrict__ aol) {
    __shared__ ushort_t Ks[2][64 * 128];   // row j: [kh 64 | kl 64], 16 chunks swizzled
    __shared__ ushort_t Vs[2][64 * 64];    // row d: vh 64, 8 chunks swizzled
    __shared__ ushort_t Ps[4][16 * 72];

    int tid = threadIdx.x;
    int w = tid >> 6, lane = tid & 63;
    int quad = lane >> 4, l15 = lane & 15;
    int rx = l15 & 7;
    int qt = 31 - blockIdx.x;           // longest blocks first (causal imbalance)
    int bh = blockIdx.y;
    int b = bh >> 4, h = bh & 15;
    int i0 = qt * 64, r0 = i0 + w * 16;
    const int nIter = qt + 2;           // j-tiles: j0 = 0,64,...,(qt+1)*64

    // --- staging: K (4 chunks) + V (2 chunks) for one j-tile into given buffers ---
    auto stage = [&](int j0, ushort_t* kd, ushort_t* vd) {
        #pragma unroll
        for (int c = 0; c < 4; ++c) {        // K: 1024 chunks
            int idx = c * 256 + tid;
            int r = idx >> 4, cl = idx & 15;
            int cg = (cl & 8) | ((cl ^ (r & 7)) & 7);
            const ushort_t* g = ((cg & 8) ? Kl : Kh)
                + ((size_t)bh * 2112 + j0 + r) * 64 + (cg & 7) * 8;
            gl_lds16(g, &kd[(c * 256 + w * 64) * 8]);
        }
        #pragma unroll
        for (int c = 0; c < 2; ++c) {        // V: 512 chunks
            int idx = c * 256 + tid;
            int r = idx >> 3, cl = idx & 7;
            int cg = cl ^ (r & 7);
            const ushort_t* g = VTh + ((size_t)bh * 64 + r) * 2112 + j0 + cg * 8;
            gl_lds16(g, &vd[(c * 256 + w * 64) * 8]);
        }
    };

    // --- register prefetch of bias + key-mask for one j-tile ---
    float bv_n[4][4];
    int km_n[4];
    auto prefetchB = [&](int j0n) {
        #pragma unroll
        for (int jt = 0; jt < 4; ++jt) {
            int jg = j0n + jt * 16 + l15;
            km_n[jt] = (jg < 2) ? 1 : (jg < 2050 ? mask[b * 2048 + jg - 2] : 0);
            #pragma unroll
            for (int reg = 0; reg < 4; ++reg) {
                int ig = r0 + quad * 4 + reg;
                bv_n[jt][reg] = (jg >= 2 && jg < 2050)
                    ? bias[((size_t)h * 2048 + ig) * 2048 + (jg - 2)] : 0.f;
            }
        }
    };

    // issue tile-0 staging + prefetch first, then overlap Q-frag loads with it
    stage(0, Ks[0], Vs[0]);
    prefetchB(0);

    bf16x8_t aqh[2], aql[2];
    {
        size_t qbase = ((size_t)bh * 2048 + r0 + l15) * 64 + quad * 8;
        aqh[0] = *(const bf16x8_t*)&Qh[qbase];
        aqh[1] = *(const bf16x8_t*)&Qh[qbase + 32];
        aql[0] = *(const bf16x8_t*)&Ql[qbase];
        aql[1] = *(const bf16x8_t*)&Ql[qbase + 32];
    }

    floatx4 o_acc[4];
    float l_acc[4];
    #pragma unroll
    for (int dt = 0; dt < 4; ++dt)
        #pragma unroll
        for (int v = 0; v < 4; ++v) o_acc[dt][v] = 0.f;
    #pragma unroll
    for (int r = 0; r < 4; ++r) l_acc[r] = 0.f;

    __syncthreads();                      // drains tile-0 staging (vmcnt 0)

    for (int it = 0; it < nIter; ++it) {
        int cur = it & 1;
        int j0 = it * 64;

        // rotate prefetched bias/mask into current regs, then issue next prefetch
        float bv[4][4];
        int km[4];
        #pragma unroll
        for (int jt = 0; jt < 4; ++jt) {
            km[jt] = km_n[jt];
            #pragma unroll
            for (int reg = 0; reg < 4; ++reg) bv[jt][reg] = bv_n[jt][reg];
        }
        if (it + 1 < nIter) {
            stage(j0 + 64, Ks[cur ^ 1], Vs[cur ^ 1]);   // latency hidden under this iter
            prefetchB(j0 + 64);
        }
        const ushort_t* ks = Ks[cur];
        const ushort_t* vs = Vs[cur];

        // S = Q K^T  (C-layout: row i = quad*4+reg, col j = jt*16+l15)
        floatx4 s_acc[4];
        #pragma unroll
        for (int jt = 0; jt < 4; ++jt) {
            floatx4 acc;
            #pragma unroll
            for (int v = 0; v < 4; ++v) acc[v] = 0.f;
            int r = jt * 16 + l15;
            #pragma unroll
            for (int ks2 = 0; ks2 < 2; ++ks2) {
                int cc = ks2 * 4 + quad;
                bf16x8_t kbh = *(const bf16x8_t*)&ks[(r * 16 + (cc ^ rx)) * 8];
                bf16x8_t kbl = *(const bf16x8_t*)&ks[(r * 16 + 8 + (cc ^ rx)) * 8];
                acc = __builtin_amdgcn_mfma_f32_16x16x32_bf16(aqh[ks2], kbh, acc, 0, 0, 0);
                acc = __builtin_amdgcn_mfma_f32_16x16x32_bf16(aql[ks2], kbh, acc, 0, 0, 0);
                acc = __builtin_amdgcn_mfma_f32_16x16x32_bf16(aqh[ks2], kbl, acc, 0, 0, 0);
            }
            s_acc[jt] = acc;
        }

        // p = exp(s + bias - 16), masked; accumulate per-lane l; store P as bf16
        #pragma unroll
        for (int jt = 0; jt < 4; ++jt) {
            int jg = j0 + jt * 16 + l15;
            #pragma unroll
            for (int reg = 0; reg < 4; ++reg) {
                int ig = r0 + quad * 4 + reg;
                float sv = s_acc[jt][reg] + bv[jt][reg] - 16.0f;
                bool ok = (km[jt] != 0) && (jg <= ig + 2);
                float pv = ok ? __expf(sv) : 0.0f;
                l_acc[reg] += pv;
                Ps[w][(quad * 4 + reg) * 72 + jt * 16 + l15] = f2bf(pv);
            }
        }

        // PV: P A-frags (same-wave LDS round-trip, no barrier needed)
        #pragma unroll
        for (int ks2 = 0; ks2 < 2; ++ks2) {
            bf16x8_t pf = *(const bf16x8_t*)&Ps[w][l15 * 72 + ks2 * 32 + quad * 8];
            #pragma unroll
            for (int dt = 0; dt < 4; ++dt) {
                int r = dt * 16 + l15;
                int cc = ks2 * 4 + quad;
                bf16x8_t vh = *(const bf16x8_t*)&vs[(r * 8 + (cc ^ rx)) * 8];
                o_acc[dt] = __builtin_amdgcn_mfma_f32_16x16x32_bf16(pf, vh, o_acc[dt], 0, 0, 0);
            }
        }

        // single barrier: drains next-tile staging AND protects buffer reuse
        __syncthreads();
    }

    // reduce l over the 16 l15 lanes (lane bits 0..3), rows = quad*4+reg
    #pragma unroll
    for (int reg = 0; reg < 4; ++reg) {
        #pragma unroll
        for (int m2 = 1; m2 < 16; m2 <<= 1)
            l_acc[reg] += __shfl_xor(l_acc[reg], m2, 64);
    }
    #pragma unroll
    for (int dt = 0; dt < 4; ++dt)
        #pragma unroll
        for (int reg = 0; reg < 4; ++reg) {
            int ig = r0 + quad * 4 + reg;
            float ov = o_acc[dt][reg] / l_acc[reg];
            size_t o = ((size_t)b * 2048 + ig) * 1024 + h * 64 + dt * 16 + l15;
            ushort_t hv = f2bf(ov);
            aoh[o] = hv;
            aol[o] = f2bf(ov - bf2f(hv));
        }
}

extern "C" void kernel_launch(void* const* d_in, const int* in_sizes, int n_in,
                              void* d_out, int out_size, void* d_ws, size_t ws_size,
                              hipStream_t stream) {
    const float* x         = (const float*)d_in[0];
    const int*   mask      = (const int*)d_in[1];
    const float* attn_bias = (const float*)d_in[2];
    const float* gamma     = (const float*)d_in[3];
    const float* null_kv   = (const float*)d_in[4];
    const float* Wq        = (const float*)d_in[5];
    const float* Wkv       = (const float*)d_in[6];
    const float* q_scale   = (const float*)d_in[7];
    const float* k_scale   = (const float*)d_in[8];
    const float* Wo        = (const float*)d_in[9];

    char* ws = (char*)d_ws;
    ushort_t* xnh   = (ushort_t*)ws; ws += (size_t)4096 * 1024 * 2;
    ushort_t* xnl   = (ushort_t*)ws; ws += (size_t)4096 * 1024 * 2;
    ushort_t* xh    = (ushort_t*)ws; ws += (size_t)4096 * 1024 * 2;
    ushort_t* xl    = (ushort_t*)ws; ws += (size_t)4096 * 1024 * 2;
    ushort_t* WqTh  = (ushort_t*)ws; ws += (size_t)1024 * 1024 * 2;
    ushort_t* WqTl  = (ushort_t*)ws; ws += (size_t)1024 * 1024 * 2;
    ushort_t* WkvTh = (ushort_t*)ws; ws += (size_t)2048 * 1024 * 2;
    ushort_t* WkvTl = (ushort_t*)ws; ws += (size_t)2048 * 1024 * 2;
    ushort_t* WoTh  = (ushort_t*)ws; ws += (size_t)1024 * 1024 * 2;
    ushort_t* WoTl  = (ushort_t*)ws; ws += (size_t)1024 * 1024 * 2;
    float*    q_ws  = (float*)ws;    ws += (size_t)4096 * 1024 * 4;
    float*    kvws  = (float*)ws;    ws += (size_t)4096 * 2048 * 4;
    ushort_t* Qh    = (ushort_t*)ws; ws += (size_t)32 * 2048 * 64 * 2;
    ushort_t* Ql    = (ushort_t*)ws; ws += (size_t)32 * 2048 * 64 * 2;
    ushort_t* Kh    = (ushort_t*)ws; ws += (size_t)32 * 2112 * 64 * 2;
    ushort_t* Kl    = (ushort_t*)ws; ws += (size_t)32 * 2112 * 64 * 2;
    ushort_t* VTh   = (ushort_t*)ws; ws += (size_t)32 * 2112 * 64 * 2;
    ushort_t* aoh   = (ushort_t*)ws; ws += (size_t)4096 * 1024 * 2;
    ushort_t* aol   = (ushort_t*)ws; ws += (size_t)4096 * 1024 * 2;

    transpose_split<<<dim3(32, 32), dim3(32, 8), 0, stream>>>(Wq, WqTh, WqTl, 1024, 1024);
    transpose_split<<<dim3(64, 32), dim3(32, 8), 0, stream>>>(Wkv, WkvTh, WkvTl, 1024, 2048);
    transpose_split<<<dim3(32, 32), dim3(32, 8), 0, stream>>>(Wo, WoTh, WoTl, 1024, 1024);
    ln_split<<<4096, 256, 0, stream>>>(x, gamma, xnh, xnl, xh, xl);
    gemm_bf3_n64<<<dim3(16, 32), 256, 0, stream>>>(xnh, xnl, WqTh, WqTl, q_ws, 4096, 1024, 1024);
    gemm_bf3<<<dim3(16, 32), 256, 0, stream>>>(xh, xl, WkvTh, WkvTl, kvws, 4096, 2048, 1024);
    l2scale_q<<<16384, 256, 0, stream>>>(q_ws, q_scale, Qh, Ql);
    build_kv<<<dim3(33, 32), 256, 0, stream>>>(kvws, null_kv, k_scale, Kh, Kl, VTh);
    attn_mfma<<<dim3(32, 32), 256, 0, stream>>>(Qh, Ql, Kh, Kl, VTh, attn_bias, mask, aoh, aol);
    gemm_bf3_n64<<<dim3(16, 32), 256, 0, stream>>>(aoh, aol, WoTh, WoTl, (float*)d_out, 4096, 1024, 1024);
}